// Round 1
// baseline (4399.242 us; speedup 1.0000x reference)
//
#include <hip/hip_runtime.h>
#include <math.h>

#define THREADS 256

// ---------------- degree / normalization ----------------

__global__ __launch_bounds__(THREADS)
void deg_count_kernel(const int* __restrict__ dst, float* __restrict__ deg, int E) {
    int i = blockIdx.x * blockDim.x + threadIdx.x;
    if (i < E) atomicAdd(&deg[dst[i]], 1.0f);
}

__global__ __launch_bounds__(THREADS)
void dis_kernel(float* __restrict__ deg, int N) {
    int i = blockIdx.x * blockDim.x + threadIdx.x;
    if (i < N) deg[i] = rsqrtf(deg[i] + 1.0f);
}

// ---------------- fp32 tiled GEMM: C[M,N] = A[M,K] @ B[K,N] ----------------
// BM=64, BN=64, BK=16, 256 threads (16x16), 4x4 per-thread tile.
// Requires: N % 64 == 0, K % 16 == 0 (true here: N in {128,64}, K in {256,128}).

#define BM 64
#define BN 64
#define BK 16

__global__ __launch_bounds__(THREADS)
void sgemm_kernel(const float* __restrict__ A, const float* __restrict__ B,
                  float* __restrict__ C, int M, int N, int K) {
    __shared__ float As[BK][BM + 1];
    __shared__ float Bs[BK][BN + 1];

    const int tid = threadIdx.x;
    const int tr = tid / 16;   // 0..15
    const int tc = tid % 16;   // 0..15
    const int rowBase = blockIdx.y * BM;
    const int colBase = blockIdx.x * BN;

    float acc[4][4] = {};

    for (int k0 = 0; k0 < K; k0 += BK) {
        // load A tile (BM x BK), store transposed As[k][m]
        #pragma unroll
        for (int i = tid; i < BM * BK; i += THREADS) {
            int r = i / BK, c = i % BK;
            int gr = rowBase + r;
            As[c][r] = (gr < M) ? A[(size_t)gr * K + k0 + c] : 0.0f;
        }
        // load B tile (BK x BN)
        #pragma unroll
        for (int i = tid; i < BK * BN; i += THREADS) {
            int r = i / BN, c = i % BN;
            Bs[r][c] = B[(size_t)(k0 + r) * N + colBase + c];
        }
        __syncthreads();

        #pragma unroll
        for (int k = 0; k < BK; ++k) {
            float a[4], b[4];
            #pragma unroll
            for (int m = 0; m < 4; ++m) a[m] = As[k][tr * 4 + m];
            #pragma unroll
            for (int n = 0; n < 4; ++n) b[n] = Bs[k][tc * 4 + n];
            #pragma unroll
            for (int m = 0; m < 4; ++m)
                #pragma unroll
                for (int n = 0; n < 4; ++n)
                    acc[m][n] += a[m] * b[n];
        }
        __syncthreads();
    }

    #pragma unroll
    for (int m = 0; m < 4; ++m) {
        int gr = rowBase + tr * 4 + m;
        if (gr >= M) continue;
        #pragma unroll
        for (int n = 0; n < 4; ++n) {
            C[(size_t)gr * N + colBase + tc * 4 + n] = acc[m][n];
        }
    }
}

// ---------------- aggregation ----------------

// agg[i,f] = h[i,f] * dis[i]^2   (self-loop contribution; also zero-inits agg)
__global__ __launch_bounds__(THREADS)
void init_agg_kernel(const float* __restrict__ h, const float* __restrict__ dis,
                     float* __restrict__ agg, int N, int F) {
    int i = blockIdx.x * blockDim.x + threadIdx.x;  // float4 index
    int total = N * (F / 4);
    if (i >= total) return;
    int node = i / (F / 4);
    float d = dis[node];
    float w = d * d;
    float4 v = ((const float4*)h)[i];
    v.x *= w; v.y *= w; v.z *= w; v.w *= w;
    ((float4*)agg)[i] = v;
}

// edge-parallel scatter: agg[dst] += h[src] * (dis[src]*dis[dst])
// F/4 lanes per edge, each lane handles one float4.
__global__ __launch_bounds__(THREADS)
void edge_scatter_kernel(const float* __restrict__ h, const int* __restrict__ src,
                         const int* __restrict__ dst, const float* __restrict__ dis,
                         float* __restrict__ agg, int E, int F) {
    int lanesPerEdge = F / 4;
    int tid = blockIdx.x * blockDim.x + threadIdx.x;
    int e = tid / lanesPerEdge;
    int c = tid % lanesPerEdge;
    if (e >= E) return;
    int s = src[e];
    int d = dst[e];
    float w = dis[s] * dis[d];
    float4 hv = ((const float4*)(h + (size_t)s * F))[c];
    float* ap = agg + (size_t)d * F + (size_t)c * 4;
    atomicAdd(ap + 0, hv.x * w);
    atomicAdd(ap + 1, hv.y * w);
    atomicAdd(ap + 2, hv.z * w);
    atomicAdd(ap + 3, hv.w * w);
}

// out[i,f] = relu(agg[i,f] + b[f])
__global__ __launch_bounds__(THREADS)
void finalize_kernel(const float* __restrict__ agg, const float* __restrict__ b,
                     float* __restrict__ out, int N, int F) {
    int i = blockIdx.x * blockDim.x + threadIdx.x;  // float4 index
    int total = N * (F / 4);
    if (i >= total) return;
    int c4 = i % (F / 4);
    float4 bv = ((const float4*)b)[c4];
    float4 v = ((const float4*)agg)[i];
    v.x = fmaxf(v.x + bv.x, 0.0f);
    v.y = fmaxf(v.y + bv.y, 0.0f);
    v.z = fmaxf(v.z + bv.z, 0.0f);
    v.w = fmaxf(v.w + bv.w, 0.0f);
    ((float4*)out)[i] = v;
}

// ---------------- launch ----------------

static inline int cdiv(long long a, long long b) { return (int)((a + b - 1) / b); }

extern "C" void kernel_launch(void* const* d_in, const int* in_sizes, int n_in,
                              void* d_out, int out_size, void* d_ws, size_t ws_size,
                              hipStream_t stream) {
    const float* x  = (const float*)d_in[0];
    const int*   ei = (const int*)d_in[1];
    const float* W1 = (const float*)d_in[2];
    const float* b1 = (const float*)d_in[3];
    const float* W2 = (const float*)d_in[4];
    const float* b2 = (const float*)d_in[5];

    const int E    = in_sizes[1] / 2;
    const int hid  = in_sizes[3];            // 128
    const int outc = in_sizes[5];            // 64
    const int inc  = in_sizes[2] / hid;      // 256
    const int N    = in_sizes[0] / inc;      // 100000

    const int* src = ei;
    const int* dst = ei + E;

    // workspace layout
    char* ws = (char*)d_ws;
    float* dis = (float*)ws;                                     // N floats
    size_t off1 = ((size_t)N * 4 + 255) & ~(size_t)255;
    float* h1 = (float*)(ws + off1);                             // N*hid floats (also out1)
    size_t off2 = off1 + ((((size_t)N * hid * 4) + 255) & ~(size_t)255);
    float* agg1 = (float*)(ws + off2);                           // N*hid floats
    float* h2   = agg1;                                          // N*outc (reuse after finalize1)
    float* agg2 = agg1 + (size_t)N * outc;                       // N*outc

    float* out = (float*)d_out;

    // 1. degrees -> dis
    hipMemsetAsync(dis, 0, (size_t)N * 4, stream);
    deg_count_kernel<<<cdiv(E, THREADS), THREADS, 0, stream>>>(dst, dis, E);
    dis_kernel<<<cdiv(N, THREADS), THREADS, 0, stream>>>(dis, N);

    // ---- layer 1 ----
    {
        dim3 grid(hid / BN, cdiv(N, BM));
        sgemm_kernel<<<grid, THREADS, 0, stream>>>(x, W1, h1, N, hid, inc);
    }
    init_agg_kernel<<<cdiv((long long)N * hid / 4, THREADS), THREADS, 0, stream>>>(h1, dis, agg1, N, hid);
    edge_scatter_kernel<<<cdiv((long long)E * (hid / 4), THREADS), THREADS, 0, stream>>>(
        h1, src, dst, dis, agg1, E, hid);
    finalize_kernel<<<cdiv((long long)N * hid / 4, THREADS), THREADS, 0, stream>>>(agg1, b1, h1, N, hid);

    // ---- layer 2 ----
    {
        dim3 grid(outc / BN, cdiv(N, BM));
        sgemm_kernel<<<grid, THREADS, 0, stream>>>(h1, W2, h2, N, outc, hid);
    }
    init_agg_kernel<<<cdiv((long long)N * outc / 4, THREADS), THREADS, 0, stream>>>(h2, dis, agg2, N, outc);
    edge_scatter_kernel<<<cdiv((long long)E * (outc / 4), THREADS), THREADS, 0, stream>>>(
        h2, src, dst, dis, agg2, E, outc);
    finalize_kernel<<<cdiv((long long)N * outc / 4, THREADS), THREADS, 0, stream>>>(agg2, b2, out, N, outc);
}

// Round 2
// 638.750 us; speedup vs baseline: 6.8873x; 6.8873x over previous
//
#include <hip/hip_runtime.h>
#include <math.h>

#define THREADS 256

static inline int cdiv(long long a, long long b) { return (int)((a + b - 1) / b); }

// ================= degree / normalization =================

__global__ __launch_bounds__(THREADS)
void hist_kernel(const int* __restrict__ dst, int* __restrict__ deg, int E) {
    int i = blockIdx.x * blockDim.x + threadIdx.x;
    if (i < E) atomicAdd(&deg[dst[i]], 1);
}

__global__ __launch_bounds__(THREADS)
void dis_from_deg_kernel(const int* __restrict__ deg, float* __restrict__ dis, int N) {
    int i = blockIdx.x * blockDim.x + threadIdx.x;
    if (i < N) dis[i] = rsqrtf((float)deg[i] + 1.0f);
}

// ================= exclusive scan (N <= 256*1024) =================

#define SCAN_BLOCK 256
#define SCAN_ITEMS 4   // 1024 elements per block

__global__ __launch_bounds__(SCAN_BLOCK)
void scan_block_kernel(const int* __restrict__ in, int* __restrict__ out,
                       int* __restrict__ blockSums, int n) {
    __shared__ int sdata[SCAN_BLOCK];
    int base = blockIdx.x * (SCAN_BLOCK * SCAN_ITEMS);
    int tid = threadIdx.x;
    int v[SCAN_ITEMS];
    int sum = 0;
    #pragma unroll
    for (int k = 0; k < SCAN_ITEMS; ++k) {
        int idx = base + tid * SCAN_ITEMS + k;
        v[k] = (idx < n) ? in[idx] : 0;
        sum += v[k];
    }
    sdata[tid] = sum;
    __syncthreads();
    for (int off = 1; off < SCAN_BLOCK; off <<= 1) {
        int t = (tid >= off) ? sdata[tid - off] : 0;
        __syncthreads();
        sdata[tid] += t;
        __syncthreads();
    }
    if (tid == SCAN_BLOCK - 1) blockSums[blockIdx.x] = sdata[SCAN_BLOCK - 1];
    int run = (tid == 0) ? 0 : sdata[tid - 1];
    #pragma unroll
    for (int k = 0; k < SCAN_ITEMS; ++k) {
        int idx = base + tid * SCAN_ITEMS + k;
        if (idx < n) out[idx] = run;
        run += v[k];
    }
}

__global__ __launch_bounds__(SCAN_BLOCK)
void scan_sums_kernel(int* __restrict__ blockSums, int nB) {
    __shared__ int sdata[SCAN_BLOCK];
    int tid = threadIdx.x;
    sdata[tid] = (tid < nB) ? blockSums[tid] : 0;
    __syncthreads();
    for (int off = 1; off < SCAN_BLOCK; off <<= 1) {
        int t = (tid >= off) ? sdata[tid - off] : 0;
        __syncthreads();
        sdata[tid] += t;
        __syncthreads();
    }
    int excl = (tid == 0) ? 0 : sdata[tid - 1];
    if (tid < nB) blockSums[tid] = excl;
}

__global__ __launch_bounds__(SCAN_BLOCK)
void scan_add_kernel(int* __restrict__ out, const int* __restrict__ blockSums, int n) {
    int base = blockIdx.x * (SCAN_BLOCK * SCAN_ITEMS);
    int add = blockSums[blockIdx.x];
    #pragma unroll
    for (int k = 0; k < SCAN_ITEMS; ++k) {
        int idx = base + threadIdx.x * SCAN_ITEMS + k;
        if (idx < n) out[idx] += add;
    }
}

__global__ void set_last_kernel(int* __restrict__ rowptr, int N, int E) {
    rowptr[N] = E;
}

// ================= CSR fill =================

__global__ __launch_bounds__(THREADS)
void fill_col_kernel(const int* __restrict__ src, const int* __restrict__ dst,
                     const int* __restrict__ rowptr, int* __restrict__ cursor,
                     int* __restrict__ col, int E) {
    int e = blockIdx.x * blockDim.x + threadIdx.x;
    if (e >= E) return;
    int d = dst[e];
    int pos = rowptr[d] + atomicAdd(&cursor[d], 1);
    col[pos] = src[e];
}

// ================= fused gather aggregation + bias + relu =================
// one wave per node; VEC floats per lane (F = 64*VEC)

template<int F, int VEC>
__global__ __launch_bounds__(THREADS)
void gather_kernel(const float* __restrict__ h, const int* __restrict__ col,
                   const int* __restrict__ rowptr, const float* __restrict__ dis,
                   const float* __restrict__ bias, float* __restrict__ out, int N) {
    int wid = (int)((blockIdx.x * (long long)blockDim.x + threadIdx.x) >> 6);
    int lane = threadIdx.x & 63;
    if (wid >= N) return;
    const int node = wid;
    const float di = dis[node];

    float acc[VEC];
    {
        const float* hrow = h + (size_t)node * F;
        float w = di * di;
        #pragma unroll
        for (int k = 0; k < VEC; ++k) acc[k] = hrow[lane * VEC + k] * w;
    }

    int start = rowptr[node], end = rowptr[node + 1];
    int s_next = (start < end) ? col[start] : 0;
    for (int j = start; j < end; ++j) {
        int s = s_next;
        if (j + 1 < end) s_next = col[j + 1];
        float w = dis[s] * di;
        const float* hs = h + (size_t)s * F;
        #pragma unroll
        for (int k = 0; k < VEC; ++k) acc[k] += hs[lane * VEC + k] * w;
    }

    float* orow = out + (size_t)node * F;
    #pragma unroll
    for (int k = 0; k < VEC; ++k) {
        float v = acc[k] + bias[lane * VEC + k];
        orow[lane * VEC + k] = fmaxf(v, 0.0f);
    }
}

// ================= fp32 tiled GEMM (round-0, verified) =================

#define BM 64
#define BN 64
#define BK 16

__global__ __launch_bounds__(THREADS)
void sgemm_kernel(const float* __restrict__ A, const float* __restrict__ B,
                  float* __restrict__ C, int M, int N, int K) {
    __shared__ float As[BK][BM + 1];
    __shared__ float Bs[BK][BN + 1];

    const int tid = threadIdx.x;
    const int tr = tid / 16;
    const int tc = tid % 16;
    const int rowBase = blockIdx.y * BM;
    const int colBase = blockIdx.x * BN;

    float acc[4][4] = {};

    for (int k0 = 0; k0 < K; k0 += BK) {
        #pragma unroll
        for (int i = tid; i < BM * BK; i += THREADS) {
            int r = i / BK, c = i % BK;
            int gr = rowBase + r;
            As[c][r] = (gr < M) ? A[(size_t)gr * K + k0 + c] : 0.0f;
        }
        #pragma unroll
        for (int i = tid; i < BK * BN; i += THREADS) {
            int r = i / BN, c = i % BN;
            Bs[r][c] = B[(size_t)(k0 + r) * N + colBase + c];
        }
        __syncthreads();

        #pragma unroll
        for (int k = 0; k < BK; ++k) {
            float a[4], b[4];
            #pragma unroll
            for (int m = 0; m < 4; ++m) a[m] = As[k][tr * 4 + m];
            #pragma unroll
            for (int n = 0; n < 4; ++n) b[n] = Bs[k][tc * 4 + n];
            #pragma unroll
            for (int m = 0; m < 4; ++m)
                #pragma unroll
                for (int n = 0; n < 4; ++n)
                    acc[m][n] += a[m] * b[n];
        }
        __syncthreads();
    }

    #pragma unroll
    for (int m = 0; m < 4; ++m) {
        int gr = rowBase + tr * 4 + m;
        if (gr >= M) continue;
        #pragma unroll
        for (int n = 0; n < 4; ++n) {
            C[(size_t)gr * N + colBase + tc * 4 + n] = acc[m][n];
        }
    }
}

// ================= fallback (round-0 atomic path) kernels =================

__global__ __launch_bounds__(THREADS)
void init_agg_kernel(const float* __restrict__ h, const float* __restrict__ dis,
                     float* __restrict__ agg, int N, int F) {
    int i = blockIdx.x * blockDim.x + threadIdx.x;
    int total = N * (F / 4);
    if (i >= total) return;
    int node = i / (F / 4);
    float d = dis[node];
    float w = d * d;
    float4 v = ((const float4*)h)[i];
    v.x *= w; v.y *= w; v.z *= w; v.w *= w;
    ((float4*)agg)[i] = v;
}

__global__ __launch_bounds__(THREADS)
void edge_scatter_kernel(const float* __restrict__ h, const int* __restrict__ src,
                         const int* __restrict__ dst, const float* __restrict__ dis,
                         float* __restrict__ agg, int E, int F) {
    int lanesPerEdge = F / 4;
    int tid = blockIdx.x * blockDim.x + threadIdx.x;
    int e = tid / lanesPerEdge;
    int c = tid % lanesPerEdge;
    if (e >= E) return;
    int s = src[e];
    int d = dst[e];
    float w = dis[s] * dis[d];
    float4 hv = ((const float4*)(h + (size_t)s * F))[c];
    float* ap = agg + (size_t)d * F + (size_t)c * 4;
    atomicAdd(ap + 0, hv.x * w);
    atomicAdd(ap + 1, hv.y * w);
    atomicAdd(ap + 2, hv.z * w);
    atomicAdd(ap + 3, hv.w * w);
}

__global__ __launch_bounds__(THREADS)
void finalize_kernel(const float* __restrict__ agg, const float* __restrict__ b,
                     float* __restrict__ out, int N, int F) {
    int i = blockIdx.x * blockDim.x + threadIdx.x;
    int total = N * (F / 4);
    if (i >= total) return;
    int c4 = i % (F / 4);
    float4 bv = ((const float4*)b)[c4];
    float4 v = ((const float4*)agg)[i];
    v.x = fmaxf(v.x + bv.x, 0.0f);
    v.y = fmaxf(v.y + bv.y, 0.0f);
    v.z = fmaxf(v.z + bv.z, 0.0f);
    v.w = fmaxf(v.w + bv.w, 0.0f);
    ((float4*)out)[i] = v;
}

// ================= launch =================

extern "C" void kernel_launch(void* const* d_in, const int* in_sizes, int n_in,
                              void* d_out, int out_size, void* d_ws, size_t ws_size,
                              hipStream_t stream) {
    const float* x  = (const float*)d_in[0];
    const int*   ei = (const int*)d_in[1];
    const float* W1 = (const float*)d_in[2];
    const float* b1 = (const float*)d_in[3];
    const float* W2 = (const float*)d_in[4];
    const float* b2 = (const float*)d_in[5];

    const int E    = in_sizes[1] / 2;
    const int hid  = in_sizes[3];            // 128
    const int outc = in_sizes[5];            // 64
    const int inc  = in_sizes[2] / hid;      // 256
    const int N    = in_sizes[0] / inc;      // 100000

    const int* src = ei;
    const int* dst = ei + E;
    float* out = (float*)d_out;
    char* ws = (char*)d_ws;

    auto al = [](size_t v) { return (v + 255) & ~(size_t)255; };
    size_t o_dis = 0;
    size_t o_deg = al(o_dis + (size_t)N * 4);
    size_t o_rp  = al(o_deg + (size_t)N * 4);
    size_t o_bs  = al(o_rp + ((size_t)N + 1) * 4);
    size_t o_col = al(o_bs + 4096);
    size_t o_A   = al(o_col + (size_t)E * 4);
    size_t o_B   = al(o_A + (size_t)N * hid * 4);
    size_t need  = o_B + (size_t)N * hid * 4;

    if (ws_size >= need && N <= SCAN_BLOCK * SCAN_BLOCK * SCAN_ITEMS && hid == 128 && outc == 64) {
        // ---------- CSR gather path ----------
        float* dis    = (float*)(ws + o_dis);
        int*   deg    = (int*)(ws + o_deg);     // also cursor
        int*   rowptr = (int*)(ws + o_rp);
        int*   bsums  = (int*)(ws + o_bs);
        int*   col    = (int*)(ws + o_col);
        float* bufA   = (float*)(ws + o_A);     // h1, later h2
        float* bufB   = (float*)(ws + o_B);     // out1

        // degrees
        hipMemsetAsync(deg, 0, (size_t)N * 4, stream);
        hist_kernel<<<cdiv(E, THREADS), THREADS, 0, stream>>>(dst, deg, E);
        dis_from_deg_kernel<<<cdiv(N, THREADS), THREADS, 0, stream>>>(deg, dis, N);

        // rowptr = exclusive_scan(deg)
        int nB = cdiv(N, SCAN_BLOCK * SCAN_ITEMS);
        scan_block_kernel<<<nB, SCAN_BLOCK, 0, stream>>>(deg, rowptr, bsums, N);
        scan_sums_kernel<<<1, SCAN_BLOCK, 0, stream>>>(bsums, nB);
        scan_add_kernel<<<nB, SCAN_BLOCK, 0, stream>>>(rowptr, bsums, N);
        set_last_kernel<<<1, 1, 0, stream>>>(rowptr, N, E);

        // col (sorted by dst)
        hipMemsetAsync(deg, 0, (size_t)N * 4, stream);
        fill_col_kernel<<<cdiv(E, THREADS), THREADS, 0, stream>>>(src, dst, rowptr, deg, col, E);

        // ---- layer 1 ----
        {
            dim3 grid(hid / BN, cdiv(N, BM));
            sgemm_kernel<<<grid, THREADS, 0, stream>>>(x, W1, bufA, N, hid, inc);
        }
        gather_kernel<128, 2><<<cdiv((long long)N * 64, THREADS), THREADS, 0, stream>>>(
            bufA, col, rowptr, dis, b1, bufB, N);

        // ---- layer 2 ----
        {
            dim3 grid(outc / BN, cdiv(N, BM));
            sgemm_kernel<<<grid, THREADS, 0, stream>>>(bufB, W2, bufA, N, outc, hid);
        }
        gather_kernel<64, 1><<<cdiv((long long)N * 64, THREADS), THREADS, 0, stream>>>(
            bufA, col, rowptr, dis, b2, out, N);
        return;
    }

    // ---------- fallback: round-0 atomic path ----------
    float* dis = (float*)ws;
    size_t off1 = ((size_t)N * 4 + 255) & ~(size_t)255;
    float* h1 = (float*)(ws + off1);
    size_t off2 = off1 + ((((size_t)N * hid * 4) + 255) & ~(size_t)255);
    float* agg1 = (float*)(ws + off2);
    float* h2   = agg1;
    float* agg2 = agg1 + (size_t)N * outc;

    hipMemsetAsync(dis, 0, (size_t)N * 4, stream);
    // reuse float histogram via int kernel on raw bits is wrong; use dedicated float path:
    // count degrees with float atomics (as round 0)
    {
        // simple float histogram
        struct L {
            static __global__ void k(const int* dst, float* deg, int E) {
                int i = blockIdx.x * blockDim.x + threadIdx.x;
                if (i < E) atomicAdd(&deg[dst[i]], 1.0f);
            }
        };
        hipLaunchKernelGGL(L::k, dim3(cdiv(E, THREADS)), dim3(THREADS), 0, stream, dst, dis, E);
    }
    {
        struct L {
            static __global__ void k(float* deg, int N) {
                int i = blockIdx.x * blockDim.x + threadIdx.x;
                if (i < N) deg[i] = rsqrtf(deg[i] + 1.0f);
            }
        };
        hipLaunchKernelGGL(L::k, dim3(cdiv(N, THREADS)), dim3(THREADS), 0, stream, dis, N);
    }

    {
        dim3 grid(hid / BN, cdiv(N, BM));
        sgemm_kernel<<<grid, THREADS, 0, stream>>>(x, W1, h1, N, hid, inc);
    }
    init_agg_kernel<<<cdiv((long long)N * hid / 4, THREADS), THREADS, 0, stream>>>(h1, dis, agg1, N, hid);
    edge_scatter_kernel<<<cdiv((long long)E * (hid / 4), THREADS), THREADS, 0, stream>>>(
        h1, src, dst, dis, agg1, E, hid);
    finalize_kernel<<<cdiv((long long)N * hid / 4, THREADS), THREADS, 0, stream>>>(agg1, b1, h1, N, hid);

    {
        dim3 grid(outc / BN, cdiv(N, BM));
        sgemm_kernel<<<grid, THREADS, 0, stream>>>(h1, W2, h2, N, outc, hid);
    }
    init_agg_kernel<<<cdiv((long long)N * outc / 4, THREADS), THREADS, 0, stream>>>(h2, dis, agg2, N, outc);
    edge_scatter_kernel<<<cdiv((long long)E * (outc / 4), THREADS), THREADS, 0, stream>>>(
        h2, src, dst, dis, agg2, E, outc);
    finalize_kernel<<<cdiv((long long)N * outc / 4, THREADS), THREADS, 0, stream>>>(agg2, b2, out, N, outc);
}

// Round 3
// 475.351 us; speedup vs baseline: 9.2547x; 1.3437x over previous
//
#include <hip/hip_runtime.h>
#include <math.h>

#define THREADS 256

static inline int cdiv(long long a, long long b) { return (int)((a + b - 1) / b); }

typedef __attribute__((ext_vector_type(8))) short bf16x8;
typedef __attribute__((ext_vector_type(4))) float f32x4;

__device__ inline unsigned f2bf_rne_u(float f) {
    unsigned u = __builtin_bit_cast(unsigned, f);
    return (u + 0x7FFFu + ((u >> 16) & 1u)) >> 16;
}
__device__ inline float bfu2f(unsigned h) {
    unsigned u = h << 16;
    return __builtin_bit_cast(float, u);
}

// ================= degree / normalization =================

__global__ __launch_bounds__(THREADS)
void hist_kernel(const int* __restrict__ dst, int* __restrict__ deg, int E) {
    int i = blockIdx.x * blockDim.x + threadIdx.x;
    if (i < E) atomicAdd(&deg[dst[i]], 1);
}

__global__ __launch_bounds__(THREADS)
void dis_from_deg_kernel(const int* __restrict__ deg, float* __restrict__ dis, int N) {
    int i = blockIdx.x * blockDim.x + threadIdx.x;
    if (i < N) dis[i] = rsqrtf((float)deg[i] + 1.0f);
}

// ================= exclusive scan (N <= 256*1024) =================

#define SCAN_BLOCK 256
#define SCAN_ITEMS 4   // 1024 elements per block

__global__ __launch_bounds__(SCAN_BLOCK)
void scan_block_kernel(const int* __restrict__ in, int* __restrict__ out,
                       int* __restrict__ blockSums, int n) {
    __shared__ int sdata[SCAN_BLOCK];
    int base = blockIdx.x * (SCAN_BLOCK * SCAN_ITEMS);
    int tid = threadIdx.x;
    int v[SCAN_ITEMS];
    int sum = 0;
    #pragma unroll
    for (int k = 0; k < SCAN_ITEMS; ++k) {
        int idx = base + tid * SCAN_ITEMS + k;
        v[k] = (idx < n) ? in[idx] : 0;
        sum += v[k];
    }
    sdata[tid] = sum;
    __syncthreads();
    for (int off = 1; off < SCAN_BLOCK; off <<= 1) {
        int t = (tid >= off) ? sdata[tid - off] : 0;
        __syncthreads();
        sdata[tid] += t;
        __syncthreads();
    }
    if (tid == SCAN_BLOCK - 1) blockSums[blockIdx.x] = sdata[SCAN_BLOCK - 1];
    int run = (tid == 0) ? 0 : sdata[tid - 1];
    #pragma unroll
    for (int k = 0; k < SCAN_ITEMS; ++k) {
        int idx = base + tid * SCAN_ITEMS + k;
        if (idx < n) out[idx] = run;
        run += v[k];
    }
}

__global__ __launch_bounds__(SCAN_BLOCK)
void scan_sums_kernel(int* __restrict__ blockSums, int nB) {
    __shared__ int sdata[SCAN_BLOCK];
    int tid = threadIdx.x;
    sdata[tid] = (tid < nB) ? blockSums[tid] : 0;
    __syncthreads();
    for (int off = 1; off < SCAN_BLOCK; off <<= 1) {
        int t = (tid >= off) ? sdata[tid - off] : 0;
        __syncthreads();
        sdata[tid] += t;
        __syncthreads();
    }
    int excl = (tid == 0) ? 0 : sdata[tid - 1];
    if (tid < nB) blockSums[tid] = excl;
}

__global__ __launch_bounds__(SCAN_BLOCK)
void scan_add_kernel(int* __restrict__ out, const int* __restrict__ blockSums, int n) {
    int base = blockIdx.x * (SCAN_BLOCK * SCAN_ITEMS);
    int add = blockSums[blockIdx.x];
    #pragma unroll
    for (int k = 0; k < SCAN_ITEMS; ++k) {
        int idx = base + threadIdx.x * SCAN_ITEMS + k;
        if (idx < n) out[idx] += add;
    }
}

__global__ void set_last_kernel(int* __restrict__ rowptr, int N, int E) {
    rowptr[N] = E;
}

// ================= CSR fill =================

__global__ __launch_bounds__(THREADS)
void fill_col_kernel(const int* __restrict__ src, const int* __restrict__ dst,
                     const int* __restrict__ rowptr, int* __restrict__ cursor,
                     int* __restrict__ col, int E) {
    int e = blockIdx.x * blockDim.x + threadIdx.x;
    if (e >= E) return;
    int d = dst[e];
    int pos = rowptr[d] + atomicAdd(&cursor[d], 1);
    col[pos] = src[e];
}

// ================= fused gather aggregation + bias + relu =================
// one wave per node; VEC floats per lane (F = 64*VEC)

template<int F, int VEC>
__global__ __launch_bounds__(THREADS)
void gather_kernel(const float* __restrict__ h, const int* __restrict__ col,
                   const int* __restrict__ rowptr, const float* __restrict__ dis,
                   const float* __restrict__ bias, float* __restrict__ out, int N) {
    int wid = (int)((blockIdx.x * (long long)blockDim.x + threadIdx.x) >> 6);
    int lane = threadIdx.x & 63;
    if (wid >= N) return;
    const int node = wid;
    const float di = dis[node];

    float acc[VEC];
    {
        const float* hrow = h + (size_t)node * F;
        float w = di * di;
        #pragma unroll
        for (int k = 0; k < VEC; ++k) acc[k] = hrow[lane * VEC + k] * w;
    }

    int start = rowptr[node], end = rowptr[node + 1];
    int s_next = (start < end) ? col[start] : 0;
    for (int j = start; j < end; ++j) {
        int s = s_next;
        if (j + 1 < end) s_next = col[j + 1];
        float w = dis[s] * di;
        const float* hs = h + (size_t)s * F;
        #pragma unroll
        for (int k = 0; k < VEC; ++k) acc[k] += hs[lane * VEC + k] * w;
    }

    float* orow = out + (size_t)node * F;
    #pragma unroll
    for (int k = 0; k < VEC; ++k) {
        float v = acc[k] + bias[lane * VEC + k];
        orow[lane * VEC + k] = fmaxf(v, 0.0f);
    }
}

// ================= split-bf16 MFMA GEMM =================
// C[M, N] = A[M, K] @ W[K, N], N = NCT*16, K = KS*32.
// 3-term split: A ~ Ahi+Alo, W ~ Whi+Wlo; C ~ AhiWhi + AhiWlo + AloWhi.
// W pre-packed into per-lane MFMA fragments (hi/lo) by make_bfrag_kernel.
// Frag layout: frag[(ks*NCT+ct)*1024 + sel*512 + lane*8 + j] (shorts), sel=0 hi, 1 lo.

template<int NCT, int KS>
__global__ __launch_bounds__(64)
void make_bfrag_kernel(const float* __restrict__ W, short* __restrict__ frag) {
    constexpr int Nn = NCT * 16;
    int lane = threadIdx.x;           // 0..63
    int ctks = blockIdx.x;            // ks*NCT + ct
    int ct = ctks % NCT;
    int ks = ctks / NCT;
    int colc = ct * 16 + (lane & 15);
    int kbase = ks * 32 + (lane >> 4) * 8;
    short* base = frag + (size_t)ctks * 1024 + lane * 8;
    #pragma unroll
    for (int j = 0; j < 8; ++j) {
        float v = W[(size_t)(kbase + j) * Nn + colc];
        unsigned h = f2bf_rne_u(v);
        base[j] = (short)h;
        base[512 + j] = (short)f2bf_rne_u(v - bfu2f(h));
    }
}

// 256 threads = 4 waves; each wave computes 32 rows (2 row-tiles) x full N.
template<int NCT, int KS>
__global__ __launch_bounds__(THREADS)
void mfma_gemm_kernel(const float* __restrict__ A, const short* __restrict__ Bfrag,
                      float* __restrict__ C, int M) {
    constexpr int K = KS * 32;
    constexpr int Nn = NCT * 16;
    const int lane = threadIdx.x & 63;
    const int wave = threadIdx.x >> 6;
    const int rowBase = blockIdx.x * 128 + wave * 32;
    const int arow0 = rowBase + (lane & 15);
    const int kgrp = (lane >> 4) * 8;

    f32x4 acc[2][NCT] = {};

    for (int ks = 0; ks < KS; ++ks) {
        const int kbase = ks * 32 + kgrp;
        bf16x8 ahi[2], alo[2];
        #pragma unroll
        for (int t = 0; t < 2; ++t) {
            int r = arow0 + t * 16;
            if (r >= M) r = M - 1;   // clamp; result rows >= M are masked on store
            const float* ap = A + (size_t)r * K + kbase;
            float4 v0 = *(const float4*)ap;
            float4 v1 = *(const float4*)(ap + 4);
            float av[8] = {v0.x, v0.y, v0.z, v0.w, v1.x, v1.y, v1.z, v1.w};
            #pragma unroll
            for (int j = 0; j < 8; ++j) {
                unsigned h = f2bf_rne_u(av[j]);
                ahi[t][j] = (short)h;
                alo[t][j] = (short)f2bf_rne_u(av[j] - bfu2f(h));
            }
        }
        #pragma unroll
        for (int ct = 0; ct < NCT; ++ct) {
            const short* bp = Bfrag + (size_t)(ks * NCT + ct) * 1024 + lane * 8;
            bf16x8 bhi = *(const bf16x8*)bp;
            bf16x8 blo = *(const bf16x8*)(bp + 512);
            #pragma unroll
            for (int t = 0; t < 2; ++t) {
                acc[t][ct] = __builtin_amdgcn_mfma_f32_16x16x32_bf16(ahi[t], bhi, acc[t][ct], 0, 0, 0);
                acc[t][ct] = __builtin_amdgcn_mfma_f32_16x16x32_bf16(ahi[t], blo, acc[t][ct], 0, 0, 0);
                acc[t][ct] = __builtin_amdgcn_mfma_f32_16x16x32_bf16(alo[t], bhi, acc[t][ct], 0, 0, 0);
            }
        }
    }

    // C/D layout: col = lane&15, row(within 16-tile) = (lane>>4)*4 + reg
    const int drow0 = rowBase + (lane >> 4) * 4;
    #pragma unroll
    for (int t = 0; t < 2; ++t) {
        #pragma unroll
        for (int r = 0; r < 4; ++r) {
            int row = drow0 + t * 16 + r;
            if (row < M) {
                float* cp = C + (size_t)row * Nn + (lane & 15);
                #pragma unroll
                for (int ct = 0; ct < NCT; ++ct)
                    cp[ct * 16] = acc[t][ct][r];
            }
        }
    }
}

// ================= fallback fp32 GEMM + atomic path (round-0, verified) =================

#define BM 64
#define BN 64
#define BK 16

__global__ __launch_bounds__(THREADS)
void sgemm_kernel(const float* __restrict__ A, const float* __restrict__ B,
                  float* __restrict__ C, int M, int N, int K) {
    __shared__ float As[BK][BM + 1];
    __shared__ float Bs[BK][BN + 1];

    const int tid = threadIdx.x;
    const int tr = tid / 16;
    const int tc = tid % 16;
    const int rowBase = blockIdx.y * BM;
    const int colBase = blockIdx.x * BN;

    float acc[4][4] = {};

    for (int k0 = 0; k0 < K; k0 += BK) {
        #pragma unroll
        for (int i = tid; i < BM * BK; i += THREADS) {
            int r = i / BK, c = i % BK;
            int gr = rowBase + r;
            As[c][r] = (gr < M) ? A[(size_t)gr * K + k0 + c] : 0.0f;
        }
        #pragma unroll
        for (int i = tid; i < BK * BN; i += THREADS) {
            int r = i / BN, c = i % BN;
            Bs[r][c] = B[(size_t)(k0 + r) * N + colBase + c];
        }
        __syncthreads();

        #pragma unroll
        for (int k = 0; k < BK; ++k) {
            float a[4], b[4];
            #pragma unroll
            for (int m = 0; m < 4; ++m) a[m] = As[k][tr * 4 + m];
            #pragma unroll
            for (int n = 0; n < 4; ++n) b[n] = Bs[k][tc * 4 + n];
            #pragma unroll
            for (int m = 0; m < 4; ++m)
                #pragma unroll
                for (int n = 0; n < 4; ++n)
                    acc[m][n] += a[m] * b[n];
        }
        __syncthreads();
    }

    #pragma unroll
    for (int m = 0; m < 4; ++m) {
        int gr = rowBase + tr * 4 + m;
        if (gr >= M) continue;
        #pragma unroll
        for (int n = 0; n < 4; ++n) {
            C[(size_t)gr * N + colBase + tc * 4 + n] = acc[m][n];
        }
    }
}

__global__ __launch_bounds__(THREADS)
void init_agg_kernel(const float* __restrict__ h, const float* __restrict__ dis,
                     float* __restrict__ agg, int N, int F) {
    int i = blockIdx.x * blockDim.x + threadIdx.x;
    int total = N * (F / 4);
    if (i >= total) return;
    int node = i / (F / 4);
    float d = dis[node];
    float w = d * d;
    float4 v = ((const float4*)h)[i];
    v.x *= w; v.y *= w; v.z *= w; v.w *= w;
    ((float4*)agg)[i] = v;
}

__global__ __launch_bounds__(THREADS)
void edge_scatter_kernel(const float* __restrict__ h, const int* __restrict__ src,
                         const int* __restrict__ dst, const float* __restrict__ dis,
                         float* __restrict__ agg, int E, int F) {
    int lanesPerEdge = F / 4;
    int tid = blockIdx.x * blockDim.x + threadIdx.x;
    int e = tid / lanesPerEdge;
    int c = tid % lanesPerEdge;
    if (e >= E) return;
    int s = src[e];
    int d = dst[e];
    float w = dis[s] * dis[d];
    float4 hv = ((const float4*)(h + (size_t)s * F))[c];
    float* ap = agg + (size_t)d * F + (size_t)c * 4;
    atomicAdd(ap + 0, hv.x * w);
    atomicAdd(ap + 1, hv.y * w);
    atomicAdd(ap + 2, hv.z * w);
    atomicAdd(ap + 3, hv.w * w);
}

__global__ __launch_bounds__(THREADS)
void finalize_kernel(const float* __restrict__ agg, const float* __restrict__ b,
                     float* __restrict__ out, int N, int F) {
    int i = blockIdx.x * blockDim.x + threadIdx.x;
    int total = N * (F / 4);
    if (i >= total) return;
    int c4 = i % (F / 4);
    float4 bv = ((const float4*)b)[c4];
    float4 v = ((const float4*)agg)[i];
    v.x = fmaxf(v.x + bv.x, 0.0f);
    v.y = fmaxf(v.y + bv.y, 0.0f);
    v.z = fmaxf(v.z + bv.z, 0.0f);
    v.w = fmaxf(v.w + bv.w, 0.0f);
    ((float4*)out)[i] = v;
}

__global__ __launch_bounds__(THREADS)
void fdeg_kernel(const int* __restrict__ dst, float* __restrict__ deg, int E) {
    int i = blockIdx.x * blockDim.x + threadIdx.x;
    if (i < E) atomicAdd(&deg[dst[i]], 1.0f);
}

__global__ __launch_bounds__(THREADS)
void fdis_kernel(float* __restrict__ deg, int N) {
    int i = blockIdx.x * blockDim.x + threadIdx.x;
    if (i < N) deg[i] = rsqrtf(deg[i] + 1.0f);
}

// ================= launch =================

extern "C" void kernel_launch(void* const* d_in, const int* in_sizes, int n_in,
                              void* d_out, int out_size, void* d_ws, size_t ws_size,
                              hipStream_t stream) {
    const float* x  = (const float*)d_in[0];
    const int*   ei = (const int*)d_in[1];
    const float* W1 = (const float*)d_in[2];
    const float* b1 = (const float*)d_in[3];
    const float* W2 = (const float*)d_in[4];
    const float* b2 = (const float*)d_in[5];

    const int E    = in_sizes[1] / 2;
    const int hid  = in_sizes[3];            // 128
    const int outc = in_sizes[5];            // 64
    const int inc  = in_sizes[2] / hid;      // 256
    const int N    = in_sizes[0] / inc;      // 100000

    const int* src = ei;
    const int* dst = ei + E;
    float* out = (float*)d_out;
    char* ws = (char*)d_ws;

    auto al = [](size_t v) { return (v + 255) & ~(size_t)255; };
    size_t o_dis = 0;
    size_t o_deg = al(o_dis + (size_t)N * 4);
    size_t o_rp  = al(o_deg + (size_t)N * 4);
    size_t o_bs  = al(o_rp + ((size_t)N + 1) * 4);
    size_t o_col = al(o_bs + 4096);
    size_t o_bf1 = al(o_col + (size_t)E * 4);
    size_t o_bf2 = al(o_bf1 + 131072);                 // 8*8*1024 shorts
    size_t o_A   = al(o_bf2 + 32768);                  // 4*4*1024 shorts
    size_t o_B   = al(o_A + (size_t)N * hid * 4);
    size_t need  = o_B + (size_t)N * hid * 4;

    if (ws_size >= need && N <= SCAN_BLOCK * SCAN_BLOCK * SCAN_ITEMS &&
        hid == 128 && outc == 64 && inc == 256) {
        // ---------- CSR gather + MFMA path ----------
        float* dis    = (float*)(ws + o_dis);
        int*   deg    = (int*)(ws + o_deg);     // also cursor
        int*   rowptr = (int*)(ws + o_rp);
        int*   bsums  = (int*)(ws + o_bs);
        int*   col    = (int*)(ws + o_col);
        short* bf1    = (short*)(ws + o_bf1);
        short* bf2    = (short*)(ws + o_bf2);
        float* bufA   = (float*)(ws + o_A);     // h1, later h2
        float* bufB   = (float*)(ws + o_B);     // out1

        // degrees
        hipMemsetAsync(deg, 0, (size_t)N * 4, stream);
        hist_kernel<<<cdiv(E, THREADS), THREADS, 0, stream>>>(dst, deg, E);
        dis_from_deg_kernel<<<cdiv(N, THREADS), THREADS, 0, stream>>>(deg, dis, N);

        // rowptr = exclusive_scan(deg)
        int nB = cdiv(N, SCAN_BLOCK * SCAN_ITEMS);
        scan_block_kernel<<<nB, SCAN_BLOCK, 0, stream>>>(deg, rowptr, bsums, N);
        scan_sums_kernel<<<1, SCAN_BLOCK, 0, stream>>>(bsums, nB);
        scan_add_kernel<<<nB, SCAN_BLOCK, 0, stream>>>(rowptr, bsums, N);
        set_last_kernel<<<1, 1, 0, stream>>>(rowptr, N, E);

        // col (sorted by dst)
        hipMemsetAsync(deg, 0, (size_t)N * 4, stream);
        fill_col_kernel<<<cdiv(E, THREADS), THREADS, 0, stream>>>(src, dst, rowptr, deg, col, E);

        // weight fragments
        make_bfrag_kernel<8, 8><<<64, 64, 0, stream>>>(W1, bf1);
        make_bfrag_kernel<4, 4><<<16, 64, 0, stream>>>(W2, bf2);

        // ---- layer 1 ----
        mfma_gemm_kernel<8, 8><<<cdiv(N, 128), THREADS, 0, stream>>>(x, bf1, bufA, N);
        gather_kernel<128, 2><<<cdiv((long long)N * 64, THREADS), THREADS, 0, stream>>>(
            bufA, col, rowptr, dis, b1, bufB, N);

        // ---- layer 2 ----
        mfma_gemm_kernel<4, 4><<<cdiv(N, 128), THREADS, 0, stream>>>(bufB, bf2, bufA, N);
        gather_kernel<64, 1><<<cdiv((long long)N * 64, THREADS), THREADS, 0, stream>>>(
            bufA, col, rowptr, dis, b2, out, N);
        return;
    }

    // ---------- fallback: round-0 atomic path ----------
    float* dis = (float*)ws;
    size_t off1 = ((size_t)N * 4 + 255) & ~(size_t)255;
    float* h1 = (float*)(ws + off1);
    size_t off2 = off1 + ((((size_t)N * hid * 4) + 255) & ~(size_t)255);
    float* agg1 = (float*)(ws + off2);
    float* h2   = agg1;
    float* agg2 = agg1 + (size_t)N * outc;

    hipMemsetAsync(dis, 0, (size_t)N * 4, stream);
    fdeg_kernel<<<cdiv(E, THREADS), THREADS, 0, stream>>>(dst, dis, E);
    fdis_kernel<<<cdiv(N, THREADS), THREADS, 0, stream>>>(dis, N);

    {
        dim3 grid(hid / BN, cdiv(N, BM));
        sgemm_kernel<<<grid, THREADS, 0, stream>>>(x, W1, h1, N, hid, inc);
    }
    init_agg_kernel<<<cdiv((long long)N * hid / 4, THREADS), THREADS, 0, stream>>>(h1, dis, agg1, N, hid);
    edge_scatter_kernel<<<cdiv((long long)E * (hid / 4), THREADS), THREADS, 0, stream>>>(
        h1, src, dst, dis, agg1, E, hid);
    finalize_kernel<<<cdiv((long long)N * hid / 4, THREADS), THREADS, 0, stream>>>(agg1, b1, h1, N, hid);

    {
        dim3 grid(outc / BN, cdiv(N, BM));
        sgemm_kernel<<<grid, THREADS, 0, stream>>>(h1, W2, h2, N, outc, hid);
    }
    init_agg_kernel<<<cdiv((long long)N * outc / 4, THREADS), THREADS, 0, stream>>>(h2, dis, agg2, N, outc);
    edge_scatter_kernel<<<cdiv((long long)E * (outc / 4), THREADS), THREADS, 0, stream>>>(
        h2, src, dst, dis, agg2, E, outc);
    finalize_kernel<<<cdiv((long long)N * outc / 4, THREADS), THREADS, 0, stream>>>(agg2, b2, out, N, outc);
}

// Round 4
// 450.724 us; speedup vs baseline: 9.7604x; 1.0546x over previous
//
#include <hip/hip_runtime.h>
#include <math.h>

#define THREADS 256

static inline int cdiv(long long a, long long b) { return (int)((a + b - 1) / b); }

typedef __attribute__((ext_vector_type(8))) short bf16x8;
typedef __attribute__((ext_vector_type(4))) float f32x4;

__device__ inline unsigned f2bf_rne_u(float f) {
    unsigned u = __builtin_bit_cast(unsigned, f);
    return (u + 0x7FFFu + ((u >> 16) & 1u)) >> 16;
}
__device__ inline float bfu2f(unsigned h) {
    unsigned u = h << 16;
    return __builtin_bit_cast(float, u);
}

// ================= degree / normalization =================

__global__ __launch_bounds__(THREADS)
void hist_kernel(const int* __restrict__ dst, int* __restrict__ deg, int E) {
    int i = blockIdx.x * blockDim.x + threadIdx.x;
    if (i < E) atomicAdd(&deg[dst[i]], 1);
}

__global__ __launch_bounds__(THREADS)
void dis_from_deg_kernel(const int* __restrict__ deg, float* __restrict__ dis, int N) {
    int i = blockIdx.x * blockDim.x + threadIdx.x;
    if (i < N) dis[i] = rsqrtf((float)deg[i] + 1.0f);
}

// ================= exclusive scan (N <= 256*1024) =================

#define SCAN_BLOCK 256
#define SCAN_ITEMS 4   // 1024 elements per block

__global__ __launch_bounds__(SCAN_BLOCK)
void scan_block_kernel(const int* __restrict__ in, int* __restrict__ out,
                       int* __restrict__ blockSums, int n) {
    __shared__ int sdata[SCAN_BLOCK];
    int base = blockIdx.x * (SCAN_BLOCK * SCAN_ITEMS);
    int tid = threadIdx.x;
    int v[SCAN_ITEMS];
    int sum = 0;
    #pragma unroll
    for (int k = 0; k < SCAN_ITEMS; ++k) {
        int idx = base + tid * SCAN_ITEMS + k;
        v[k] = (idx < n) ? in[idx] : 0;
        sum += v[k];
    }
    sdata[tid] = sum;
    __syncthreads();
    for (int off = 1; off < SCAN_BLOCK; off <<= 1) {
        int t = (tid >= off) ? sdata[tid - off] : 0;
        __syncthreads();
        sdata[tid] += t;
        __syncthreads();
    }
    if (tid == SCAN_BLOCK - 1) blockSums[blockIdx.x] = sdata[SCAN_BLOCK - 1];
    int run = (tid == 0) ? 0 : sdata[tid - 1];
    #pragma unroll
    for (int k = 0; k < SCAN_ITEMS; ++k) {
        int idx = base + tid * SCAN_ITEMS + k;
        if (idx < n) out[idx] = run;
        run += v[k];
    }
}

__global__ __launch_bounds__(SCAN_BLOCK)
void scan_sums_kernel(int* __restrict__ blockSums, int nB) {
    __shared__ int sdata[SCAN_BLOCK];
    int tid = threadIdx.x;
    sdata[tid] = (tid < nB) ? blockSums[tid] : 0;
    __syncthreads();
    for (int off = 1; off < SCAN_BLOCK; off <<= 1) {
        int t = (tid >= off) ? sdata[tid - off] : 0;
        __syncthreads();
        sdata[tid] += t;
        __syncthreads();
    }
    int excl = (tid == 0) ? 0 : sdata[tid - 1];
    if (tid < nB) blockSums[tid] = excl;
}

__global__ __launch_bounds__(SCAN_BLOCK)
void scan_add_kernel(int* __restrict__ out, const int* __restrict__ blockSums, int n) {
    int base = blockIdx.x * (SCAN_BLOCK * SCAN_ITEMS);
    int add = blockSums[blockIdx.x];
    #pragma unroll
    for (int k = 0; k < SCAN_ITEMS; ++k) {
        int idx = base + threadIdx.x * SCAN_ITEMS + k;
        if (idx < n) out[idx] += add;
    }
}

__global__ void set_last_kernel(int* __restrict__ rowptr, int N, int E) {
    rowptr[N] = E;
}

// ================= CSR fill =================

__global__ __launch_bounds__(THREADS)
void fill_col_kernel(const int* __restrict__ src, const int* __restrict__ dst,
                     const int* __restrict__ rowptr, int* __restrict__ cursor,
                     int* __restrict__ col, int E) {
    int e = blockIdx.x * blockDim.x + threadIdx.x;
    if (e >= E) return;
    int d = dst[e];
    int pos = rowptr[d] + atomicAdd(&cursor[d], 1);
    col[pos] = src[e];
}

// ================= fused gather aggregation (bf16 pre-scaled rows) =================
// g[i] = h[i] * dis[i] (bf16). out_i = relu(dis_i * (g_i + sum_{s in N(i)} g_s) + b).
// One wave per node; VEC bf16 elems per lane (F = 64*VEC, VEC in {1,2}).

template<int F, int VEC>
__global__ __launch_bounds__(THREADS)
void gather_bf16_kernel(const unsigned short* __restrict__ g, const int* __restrict__ col,
                        const int* __restrict__ rowptr, const float* __restrict__ dis,
                        const float* __restrict__ bias, float* __restrict__ out, int N) {
    int wid = (int)((blockIdx.x * (long long)blockDim.x + threadIdx.x) >> 6);
    int lane = threadIdx.x & 63;
    if (wid >= N) return;
    const int node = wid;
    const float di = dis[node];

    float acc0 = 0.0f, acc1 = 0.0f;

    auto loadrow = [&](int s) -> unsigned {
        if (VEC == 2) {
            return *(const unsigned*)(g + (size_t)s * F + lane * 2);
        } else {
            return (unsigned)g[(size_t)s * F + lane];
        }
    };
    auto addconv = [&](unsigned u) {
        acc0 += bfu2f(u & 0xFFFFu);
        if (VEC == 2) {
            float f1 = __builtin_bit_cast(float, u & 0xFFFF0000u);
            acc1 += f1;
        }
    };

    // self-loop row
    addconv(loadrow(node));

    int start = rowptr[node], end = rowptr[node + 1];
    int ne = end - start;
    if (ne > 0) {
        unsigned u0 = loadrow(col[start]);
        if (ne > 1) {
            unsigned u1 = loadrow(col[start + 1]);
            for (int j = start + 2; j < end; ++j) {
                int sn = col[j];
                addconv(u0);
                u0 = u1;
                u1 = loadrow(sn);
            }
            addconv(u0);
            u0 = u1;
        }
        addconv(u0);
    }

    float* orow = out + (size_t)node * F;
    {
        float v = di * acc0 + bias[lane * VEC + 0];
        orow[lane * VEC + 0] = fmaxf(v, 0.0f);
    }
    if (VEC == 2) {
        float v = di * acc1 + bias[lane * VEC + 1];
        orow[lane * VEC + 1] = fmaxf(v, 0.0f);
    }
}

// ================= split-bf16 MFMA GEMM =================
// C[M, N] = A[M, K] @ W[K, N], N = NCT*16, K = KS*32.
// 3-term split: A ~ Ahi+Alo, W ~ Whi+Wlo; C ~ AhiWhi + AhiWlo + AloWhi.
// Output: bf16 rows scaled by dis[row] (g = C*dis), feeding gather_bf16_kernel.

template<int NCT, int KS>
__global__ __launch_bounds__(64)
void make_bfrag_kernel(const float* __restrict__ W, short* __restrict__ frag) {
    constexpr int Nn = NCT * 16;
    int lane = threadIdx.x;           // 0..63
    int ctks = blockIdx.x;            // ks*NCT + ct
    int ct = ctks % NCT;
    int ks = ctks / NCT;
    int colc = ct * 16 + (lane & 15);
    int kbase = ks * 32 + (lane >> 4) * 8;
    short* base = frag + (size_t)ctks * 1024 + lane * 8;
    #pragma unroll
    for (int j = 0; j < 8; ++j) {
        float v = W[(size_t)(kbase + j) * Nn + colc];
        unsigned h = f2bf_rne_u(v);
        base[j] = (short)h;
        base[512 + j] = (short)f2bf_rne_u(v - bfu2f(h));
    }
}

// 256 threads = 4 waves; each wave computes 32 rows (2 row-tiles) x full N.
template<int NCT, int KS>
__global__ __launch_bounds__(THREADS)
void mfma_gemm_bf16out_kernel(const float* __restrict__ A, const short* __restrict__ Bfrag,
                              unsigned short* __restrict__ G, const float* __restrict__ dis,
                              int M) {
    constexpr int K = KS * 32;
    constexpr int Nn = NCT * 16;
    const int lane = threadIdx.x & 63;
    const int wave = threadIdx.x >> 6;
    const int rowBase = blockIdx.x * 128 + wave * 32;
    const int arow0 = rowBase + (lane & 15);
    const int kgrp = (lane >> 4) * 8;

    f32x4 acc[2][NCT] = {};

    for (int ks = 0; ks < KS; ++ks) {
        const int kbase = ks * 32 + kgrp;
        bf16x8 ahi[2], alo[2];
        #pragma unroll
        for (int t = 0; t < 2; ++t) {
            int r = arow0 + t * 16;
            if (r >= M) r = M - 1;   // clamp; rows >= M masked on store
            const float* ap = A + (size_t)r * K + kbase;
            float4 v0 = *(const float4*)ap;
            float4 v1 = *(const float4*)(ap + 4);
            float av[8] = {v0.x, v0.y, v0.z, v0.w, v1.x, v1.y, v1.z, v1.w};
            #pragma unroll
            for (int j = 0; j < 8; ++j) {
                unsigned h = f2bf_rne_u(av[j]);
                ahi[t][j] = (short)h;
                alo[t][j] = (short)f2bf_rne_u(av[j] - bfu2f(h));
            }
        }
        #pragma unroll
        for (int ct = 0; ct < NCT; ++ct) {
            const short* bp = Bfrag + (size_t)(ks * NCT + ct) * 1024 + lane * 8;
            bf16x8 bhi = *(const bf16x8*)bp;
            bf16x8 blo = *(const bf16x8*)(bp + 512);
            #pragma unroll
            for (int t = 0; t < 2; ++t) {
                acc[t][ct] = __builtin_amdgcn_mfma_f32_16x16x32_bf16(ahi[t], bhi, acc[t][ct], 0, 0, 0);
                acc[t][ct] = __builtin_amdgcn_mfma_f32_16x16x32_bf16(ahi[t], blo, acc[t][ct], 0, 0, 0);
                acc[t][ct] = __builtin_amdgcn_mfma_f32_16x16x32_bf16(alo[t], bhi, acc[t][ct], 0, 0, 0);
            }
        }
    }

    // C/D layout: col = lane&15, row(within 16-tile) = (lane>>4)*4 + reg
    const int drow0 = rowBase + (lane >> 4) * 4;
    #pragma unroll
    for (int t = 0; t < 2; ++t) {
        #pragma unroll
        for (int r = 0; r < 4; ++r) {
            int row = drow0 + t * 16 + r;
            if (row < M) {
                float dval = dis[row];
                unsigned short* gp = G + (size_t)row * Nn + (lane & 15);
                #pragma unroll
                for (int ct = 0; ct < NCT; ++ct)
                    gp[ct * 16] = (unsigned short)f2bf_rne_u(acc[t][ct][r] * dval);
            }
        }
    }
}

// ================= fallback fp32 GEMM + atomic path (round-0, verified) =================

#define BM 64
#define BN 64
#define BK 16

__global__ __launch_bounds__(THREADS)
void sgemm_kernel(const float* __restrict__ A, const float* __restrict__ B,
                  float* __restrict__ C, int M, int N, int K) {
    __shared__ float As[BK][BM + 1];
    __shared__ float Bs[BK][BN + 1];

    const int tid = threadIdx.x;
    const int tr = tid / 16;
    const int tc = tid % 16;
    const int rowBase = blockIdx.y * BM;
    const int colBase = blockIdx.x * BN;

    float acc[4][4] = {};

    for (int k0 = 0; k0 < K; k0 += BK) {
        #pragma unroll
        for (int i = tid; i < BM * BK; i += THREADS) {
            int r = i / BK, c = i % BK;
            int gr = rowBase + r;
            As[c][r] = (gr < M) ? A[(size_t)gr * K + k0 + c] : 0.0f;
        }
        #pragma unroll
        for (int i = tid; i < BK * BN; i += THREADS) {
            int r = i / BN, c = i % BN;
            Bs[r][c] = B[(size_t)(k0 + r) * N + colBase + c];
        }
        __syncthreads();

        #pragma unroll
        for (int k = 0; k < BK; ++k) {
            float a[4], b[4];
            #pragma unroll
            for (int m = 0; m < 4; ++m) a[m] = As[k][tr * 4 + m];
            #pragma unroll
            for (int n = 0; n < 4; ++n) b[n] = Bs[k][tc * 4 + n];
            #pragma unroll
            for (int m = 0; m < 4; ++m)
                #pragma unroll
                for (int n = 0; n < 4; ++n)
                    acc[m][n] += a[m] * b[n];
        }
        __syncthreads();
    }

    #pragma unroll
    for (int m = 0; m < 4; ++m) {
        int gr = rowBase + tr * 4 + m;
        if (gr >= M) continue;
        #pragma unroll
        for (int n = 0; n < 4; ++n) {
            C[(size_t)gr * N + colBase + tc * 4 + n] = acc[m][n];
        }
    }
}

__global__ __launch_bounds__(THREADS)
void init_agg_kernel(const float* __restrict__ h, const float* __restrict__ dis,
                     float* __restrict__ agg, int N, int F) {
    int i = blockIdx.x * blockDim.x + threadIdx.x;
    int total = N * (F / 4);
    if (i >= total) return;
    int node = i / (F / 4);
    float d = dis[node];
    float w = d * d;
    float4 v = ((const float4*)h)[i];
    v.x *= w; v.y *= w; v.z *= w; v.w *= w;
    ((float4*)agg)[i] = v;
}

__global__ __launch_bounds__(THREADS)
void edge_scatter_kernel(const float* __restrict__ h, const int* __restrict__ src,
                         const int* __restrict__ dst, const float* __restrict__ dis,
                         float* __restrict__ agg, int E, int F) {
    int lanesPerEdge = F / 4;
    int tid = blockIdx.x * blockDim.x + threadIdx.x;
    int e = tid / lanesPerEdge;
    int c = tid % lanesPerEdge;
    if (e >= E) return;
    int s = src[e];
    int d = dst[e];
    float w = dis[s] * dis[d];
    float4 hv = ((const float4*)(h + (size_t)s * F))[c];
    float* ap = agg + (size_t)d * F + (size_t)c * 4;
    atomicAdd(ap + 0, hv.x * w);
    atomicAdd(ap + 1, hv.y * w);
    atomicAdd(ap + 2, hv.z * w);
    atomicAdd(ap + 3, hv.w * w);
}

__global__ __launch_bounds__(THREADS)
void finalize_kernel(const float* __restrict__ agg, const float* __restrict__ b,
                     float* __restrict__ out, int N, int F) {
    int i = blockIdx.x * blockDim.x + threadIdx.x;
    int total = N * (F / 4);
    if (i >= total) return;
    int c4 = i % (F / 4);
    float4 bv = ((const float4*)b)[c4];
    float4 v = ((const float4*)agg)[i];
    v.x = fmaxf(v.x + bv.x, 0.0f);
    v.y = fmaxf(v.y + bv.y, 0.0f);
    v.z = fmaxf(v.z + bv.z, 0.0f);
    v.w = fmaxf(v.w + bv.w, 0.0f);
    ((float4*)out)[i] = v;
}

__global__ __launch_bounds__(THREADS)
void fdeg_kernel(const int* __restrict__ dst, float* __restrict__ deg, int E) {
    int i = blockIdx.x * blockDim.x + threadIdx.x;
    if (i < E) atomicAdd(&deg[dst[i]], 1.0f);
}

__global__ __launch_bounds__(THREADS)
void fdis_kernel(float* __restrict__ deg, int N) {
    int i = blockIdx.x * blockDim.x + threadIdx.x;
    if (i < N) deg[i] = rsqrtf(deg[i] + 1.0f);
}

// ================= launch =================

extern "C" void kernel_launch(void* const* d_in, const int* in_sizes, int n_in,
                              void* d_out, int out_size, void* d_ws, size_t ws_size,
                              hipStream_t stream) {
    const float* x  = (const float*)d_in[0];
    const int*   ei = (const int*)d_in[1];
    const float* W1 = (const float*)d_in[2];
    const float* b1 = (const float*)d_in[3];
    const float* W2 = (const float*)d_in[4];
    const float* b2 = (const float*)d_in[5];

    const int E    = in_sizes[1] / 2;
    const int hid  = in_sizes[3];            // 128
    const int outc = in_sizes[5];            // 64
    const int inc  = in_sizes[2] / hid;      // 256
    const int N    = in_sizes[0] / inc;      // 100000

    const int* src = ei;
    const int* dst = ei + E;
    float* out = (float*)d_out;
    char* ws = (char*)d_ws;

    auto al = [](size_t v) { return (v + 255) & ~(size_t)255; };
    size_t o_dis = 0;
    size_t o_deg = al(o_dis + (size_t)N * 4);
    size_t o_rp  = al(o_deg + (size_t)N * 4);
    size_t o_bs  = al(o_rp + ((size_t)N + 1) * 4);
    size_t o_col = al(o_bs + 4096);
    size_t o_bf1 = al(o_col + (size_t)E * 4);
    size_t o_bf2 = al(o_bf1 + 131072);                 // 8*8*1024 shorts
    size_t o_G   = al(o_bf2 + 32768);                  // 4*4*1024 shorts
    size_t o_B   = al(o_G + (size_t)N * hid * 2);      // g rows (bf16)
    size_t need  = o_B + (size_t)N * hid * 4;          // out1 (fp32)

    if (ws_size >= need && N <= SCAN_BLOCK * SCAN_BLOCK * SCAN_ITEMS &&
        hid == 128 && outc == 64 && inc == 256) {
        // ---------- CSR gather + MFMA path ----------
        float* dis    = (float*)(ws + o_dis);
        int*   deg    = (int*)(ws + o_deg);     // also cursor
        int*   rowptr = (int*)(ws + o_rp);
        int*   bsums  = (int*)(ws + o_bs);
        int*   col    = (int*)(ws + o_col);
        short* bf1    = (short*)(ws + o_bf1);
        short* bf2    = (short*)(ws + o_bf2);
        unsigned short* gbuf = (unsigned short*)(ws + o_G);  // g1 (N*128 bf16), later g2 (N*64)
        float* out1   = (float*)(ws + o_B);     // fp32 layer-1 output

        // degrees
        hipMemsetAsync(deg, 0, (size_t)N * 4, stream);
        hist_kernel<<<cdiv(E, THREADS), THREADS, 0, stream>>>(dst, deg, E);
        dis_from_deg_kernel<<<cdiv(N, THREADS), THREADS, 0, stream>>>(deg, dis, N);

        // rowptr = exclusive_scan(deg)
        int nB = cdiv(N, SCAN_BLOCK * SCAN_ITEMS);
        scan_block_kernel<<<nB, SCAN_BLOCK, 0, stream>>>(deg, rowptr, bsums, N);
        scan_sums_kernel<<<1, SCAN_BLOCK, 0, stream>>>(bsums, nB);
        scan_add_kernel<<<nB, SCAN_BLOCK, 0, stream>>>(rowptr, bsums, N);
        set_last_kernel<<<1, 1, 0, stream>>>(rowptr, N, E);

        // col (sorted by dst)
        hipMemsetAsync(deg, 0, (size_t)N * 4, stream);
        fill_col_kernel<<<cdiv(E, THREADS), THREADS, 0, stream>>>(src, dst, rowptr, deg, col, E);

        // weight fragments
        make_bfrag_kernel<8, 8><<<64, 64, 0, stream>>>(W1, bf1);
        make_bfrag_kernel<4, 4><<<16, 64, 0, stream>>>(W2, bf2);

        // ---- layer 1 ----
        mfma_gemm_bf16out_kernel<8, 8><<<cdiv(N, 128), THREADS, 0, stream>>>(x, bf1, gbuf, dis, N);
        gather_bf16_kernel<128, 2><<<cdiv((long long)N * 64, THREADS), THREADS, 0, stream>>>(
            gbuf, col, rowptr, dis, b1, out1, N);

        // ---- layer 2 ----
        mfma_gemm_bf16out_kernel<4, 4><<<cdiv(N, 128), THREADS, 0, stream>>>(out1, bf2, gbuf, dis, N);
        gather_bf16_kernel<64, 1><<<cdiv((long long)N * 64, THREADS), THREADS, 0, stream>>>(
            gbuf, col, rowptr, dis, b2, out, N);
        return;
    }

    // ---------- fallback: round-0 atomic path ----------
    float* dis = (float*)ws;
    size_t off1 = ((size_t)N * 4 + 255) & ~(size_t)255;
    float* h1 = (float*)(ws + off1);
    size_t off2 = off1 + ((((size_t)N * hid * 4) + 255) & ~(size_t)255);
    float* agg1 = (float*)(ws + off2);
    float* h2   = agg1;
    float* agg2 = agg1 + (size_t)N * outc;

    hipMemsetAsync(dis, 0, (size_t)N * 4, stream);
    fdeg_kernel<<<cdiv(E, THREADS), THREADS, 0, stream>>>(dst, dis, E);
    fdis_kernel<<<cdiv(N, THREADS), THREADS, 0, stream>>>(dis, N);

    {
        dim3 grid(hid / BN, cdiv(N, BM));
        sgemm_kernel<<<grid, THREADS, 0, stream>>>(x, W1, h1, N, hid, inc);
    }
    init_agg_kernel<<<cdiv((long long)N * hid / 4, THREADS), THREADS, 0, stream>>>(h1, dis, agg1, N, hid);
    edge_scatter_kernel<<<cdiv((long long)E * (hid / 4), THREADS), THREADS, 0, stream>>>(
        h1, src, dst, dis, agg1, E, hid);
    finalize_kernel<<<cdiv((long long)N * hid / 4, THREADS), THREADS, 0, stream>>>(agg1, b1, h1, N, hid);

    {
        dim3 grid(outc / BN, cdiv(N, BM));
        sgemm_kernel<<<grid, THREADS, 0, stream>>>(h1, W2, h2, N, outc, hid);
    }
    init_agg_kernel<<<cdiv((long long)N * outc / 4, THREADS), THREADS, 0, stream>>>(h2, dis, agg2, N, outc);
    edge_scatter_kernel<<<cdiv((long long)E * (outc / 4), THREADS), THREADS, 0, stream>>>(
        h2, src, dst, dis, agg2, E, outc);
    finalize_kernel<<<cdiv((long long)N * outc / 4, THREADS), THREADS, 0, stream>>>(agg2, b2, out, N, outc);
}

// Round 5
// 369.037 us; speedup vs baseline: 11.9209x; 1.2214x over previous
//
#include <hip/hip_runtime.h>
#include <math.h>

#define THREADS 256

static inline int cdiv(long long a, long long b) { return (int)((a + b - 1) / b); }

typedef __attribute__((ext_vector_type(8))) short bf16x8;
typedef __attribute__((ext_vector_type(4))) float f32x4;

__device__ inline unsigned f2bf_rne_u(float f) {
    unsigned u = __builtin_bit_cast(unsigned, f);
    return (u + 0x7FFFu + ((u >> 16) & 1u)) >> 16;
}
__device__ inline float bfu2f(unsigned h) {
    unsigned u = h << 16;
    return __builtin_bit_cast(float, u);
}

// ================= degree histogram + per-edge rank =================
// rank[e] = old count of dst[e]  (the atomic grant IS the rank within the row)

__global__ __launch_bounds__(THREADS)
void hist_rank_kernel(const int* __restrict__ dst, int* __restrict__ deg,
                      int* __restrict__ rank, int E) {
    int i = blockIdx.x * blockDim.x + threadIdx.x;
    if (i < E) rank[i] = atomicAdd(&deg[dst[i]], 1);
}

// ================= exclusive scan (N <= 256*1024), fused dis =================

#define SCAN_BLOCK 256
#define SCAN_ITEMS 4   // 1024 elements per block

__global__ __launch_bounds__(SCAN_BLOCK)
void scan_block_kernel(const int* __restrict__ in, int* __restrict__ out,
                       int* __restrict__ blockSums, float* __restrict__ dis, int n) {
    __shared__ int sdata[SCAN_BLOCK];
    int base = blockIdx.x * (SCAN_BLOCK * SCAN_ITEMS);
    int tid = threadIdx.x;
    int v[SCAN_ITEMS];
    int sum = 0;
    #pragma unroll
    for (int k = 0; k < SCAN_ITEMS; ++k) {
        int idx = base + tid * SCAN_ITEMS + k;
        v[k] = (idx < n) ? in[idx] : 0;
        if (idx < n) dis[idx] = rsqrtf((float)v[k] + 1.0f);
        sum += v[k];
    }
    sdata[tid] = sum;
    __syncthreads();
    for (int off = 1; off < SCAN_BLOCK; off <<= 1) {
        int t = (tid >= off) ? sdata[tid - off] : 0;
        __syncthreads();
        sdata[tid] += t;
        __syncthreads();
    }
    if (tid == SCAN_BLOCK - 1) blockSums[blockIdx.x] = sdata[SCAN_BLOCK - 1];
    int run = (tid == 0) ? 0 : sdata[tid - 1];
    #pragma unroll
    for (int k = 0; k < SCAN_ITEMS; ++k) {
        int idx = base + tid * SCAN_ITEMS + k;
        if (idx < n) out[idx] = run;
        run += v[k];
    }
}

__global__ __launch_bounds__(SCAN_BLOCK)
void scan_sums_kernel(int* __restrict__ blockSums, int nB) {
    __shared__ int sdata[SCAN_BLOCK];
    int tid = threadIdx.x;
    sdata[tid] = (tid < nB) ? blockSums[tid] : 0;
    __syncthreads();
    for (int off = 1; off < SCAN_BLOCK; off <<= 1) {
        int t = (tid >= off) ? sdata[tid - off] : 0;
        __syncthreads();
        sdata[tid] += t;
        __syncthreads();
    }
    int excl = (tid == 0) ? 0 : sdata[tid - 1];
    if (tid < nB) blockSums[tid] = excl;
}

__global__ __launch_bounds__(SCAN_BLOCK)
void scan_add_kernel(int* __restrict__ out, const int* __restrict__ blockSums,
                     int n, int E) {
    int base = blockIdx.x * (SCAN_BLOCK * SCAN_ITEMS);
    int add = blockSums[blockIdx.x];
    #pragma unroll
    for (int k = 0; k < SCAN_ITEMS; ++k) {
        int idx = base + threadIdx.x * SCAN_ITEMS + k;
        if (idx < n) out[idx] += add;
    }
    if (blockIdx.x == 0 && threadIdx.x == 0) out[n] = E;
}

// ================= CSR fill (atomic-free; 4 edges/thread) =================

__global__ __launch_bounds__(THREADS)
void fill_col_rank_kernel(const int* __restrict__ src, const int* __restrict__ dst,
                          const int* __restrict__ rank, const int* __restrict__ rowptr,
                          int* __restrict__ col, int E) {
    int base = (blockIdx.x * blockDim.x + threadIdx.x) * 4;
    if (base + 3 < E) {
        int4 d = *(const int4*)(dst + base);
        int4 r = *(const int4*)(rank + base);
        int4 s = *(const int4*)(src + base);
        col[rowptr[d.x] + r.x] = s.x;
        col[rowptr[d.y] + r.y] = s.y;
        col[rowptr[d.z] + r.z] = s.z;
        col[rowptr[d.w] + r.w] = s.w;
    } else {
        for (int e = base; e < E; ++e)
            col[rowptr[dst[e]] + rank[e]] = src[e];
    }
}

// ================= fused gather aggregation (bf16 pre-scaled rows) =================
// g[i] = h[i] * dis[i] (bf16). out_i = relu(dis_i * (g_i + sum_{s in N(i)} g_s) + b).
// One wave per node; VEC bf16 elems per lane (F = 64*VEC, VEC in {1,2}).

template<int F, int VEC>
__global__ __launch_bounds__(THREADS)
void gather_bf16_kernel(const unsigned short* __restrict__ g, const int* __restrict__ col,
                        const int* __restrict__ rowptr, const float* __restrict__ dis,
                        const float* __restrict__ bias, float* __restrict__ out, int N) {
    int wid = (int)((blockIdx.x * (long long)blockDim.x + threadIdx.x) >> 6);
    int lane = threadIdx.x & 63;
    if (wid >= N) return;
    const int node = wid;
    const float di = dis[node];

    float acc0 = 0.0f, acc1 = 0.0f;

    auto loadrow = [&](int s) -> unsigned {
        if (VEC == 2) {
            return *(const unsigned*)(g + (size_t)s * F + lane * 2);
        } else {
            return (unsigned)g[(size_t)s * F + lane];
        }
    };
    auto addconv = [&](unsigned u) {
        acc0 += bfu2f(u & 0xFFFFu);
        if (VEC == 2) {
            float f1 = __builtin_bit_cast(float, u & 0xFFFF0000u);
            acc1 += f1;
        }
    };

    // self-loop row
    addconv(loadrow(node));

    int start = rowptr[node], end = rowptr[node + 1];
    int ne = end - start;
    if (ne > 0) {
        unsigned u0 = loadrow(col[start]);
        if (ne > 1) {
            unsigned u1 = loadrow(col[start + 1]);
            for (int j = start + 2; j < end; ++j) {
                int sn = col[j];
                addconv(u0);
                u0 = u1;
                u1 = loadrow(sn);
            }
            addconv(u0);
            u0 = u1;
        }
        addconv(u0);
    }

    float* orow = out + (size_t)node * F;
    {
        float v = di * acc0 + bias[lane * VEC + 0];
        orow[lane * VEC + 0] = fmaxf(v, 0.0f);
    }
    if (VEC == 2) {
        float v = di * acc1 + bias[lane * VEC + 1];
        orow[lane * VEC + 1] = fmaxf(v, 0.0f);
    }
}

// ================= split-bf16 MFMA GEMM =================
// C[M, N] = A[M, K] @ W[K, N], N = NCT*16, K = KS*32.
// 3-term split: A ~ Ahi+Alo, W ~ Whi+Wlo; C ~ AhiWhi + AhiWlo + AloWhi.
// Output: bf16 rows scaled by dis[row] (g = C*dis), feeding gather_bf16_kernel.

template<int NCT, int KS>
__global__ __launch_bounds__(64)
void make_bfrag_kernel(const float* __restrict__ W, short* __restrict__ frag) {
    constexpr int Nn = NCT * 16;
    int lane = threadIdx.x;           // 0..63
    int ctks = blockIdx.x;            // ks*NCT + ct
    int ct = ctks % NCT;
    int ks = ctks / NCT;
    int colc = ct * 16 + (lane & 15);
    int kbase = ks * 32 + (lane >> 4) * 8;
    short* base = frag + (size_t)ctks * 1024 + lane * 8;
    #pragma unroll
    for (int j = 0; j < 8; ++j) {
        float v = W[(size_t)(kbase + j) * Nn + colc];
        unsigned h = f2bf_rne_u(v);
        base[j] = (short)h;
        base[512 + j] = (short)f2bf_rne_u(v - bfu2f(h));
    }
}

// 256 threads = 4 waves; each wave computes 32 rows (2 row-tiles) x full N.
template<int NCT, int KS>
__global__ __launch_bounds__(THREADS)
void mfma_gemm_bf16out_kernel(const float* __restrict__ A, const short* __restrict__ Bfrag,
                              unsigned short* __restrict__ G, const float* __restrict__ dis,
                              int M) {
    constexpr int K = KS * 32;
    constexpr int Nn = NCT * 16;
    const int lane = threadIdx.x & 63;
    const int wave = threadIdx.x >> 6;
    const int rowBase = blockIdx.x * 128 + wave * 32;
    const int arow0 = rowBase + (lane & 15);
    const int kgrp = (lane >> 4) * 8;

    f32x4 acc[2][NCT] = {};

    for (int ks = 0; ks < KS; ++ks) {
        const int kbase = ks * 32 + kgrp;
        bf16x8 ahi[2], alo[2];
        #pragma unroll
        for (int t = 0; t < 2; ++t) {
            int r = arow0 + t * 16;
            if (r >= M) r = M - 1;   // clamp; rows >= M masked on store
            const float* ap = A + (size_t)r * K + kbase;
            float4 v0 = *(const float4*)ap;
            float4 v1 = *(const float4*)(ap + 4);
            float av[8] = {v0.x, v0.y, v0.z, v0.w, v1.x, v1.y, v1.z, v1.w};
            #pragma unroll
            for (int j = 0; j < 8; ++j) {
                unsigned h = f2bf_rne_u(av[j]);
                ahi[t][j] = (short)h;
                alo[t][j] = (short)f2bf_rne_u(av[j] - bfu2f(h));
            }
        }
        #pragma unroll
        for (int ct = 0; ct < NCT; ++ct) {
            const short* bp = Bfrag + (size_t)(ks * NCT + ct) * 1024 + lane * 8;
            bf16x8 bhi = *(const bf16x8*)bp;
            bf16x8 blo = *(const bf16x8*)(bp + 512);
            #pragma unroll
            for (int t = 0; t < 2; ++t) {
                acc[t][ct] = __builtin_amdgcn_mfma_f32_16x16x32_bf16(ahi[t], bhi, acc[t][ct], 0, 0, 0);
                acc[t][ct] = __builtin_amdgcn_mfma_f32_16x16x32_bf16(ahi[t], blo, acc[t][ct], 0, 0, 0);
                acc[t][ct] = __builtin_amdgcn_mfma_f32_16x16x32_bf16(alo[t], bhi, acc[t][ct], 0, 0, 0);
            }
        }
    }

    // C/D layout: col = lane&15, row(within 16-tile) = (lane>>4)*4 + reg
    const int drow0 = rowBase + (lane >> 4) * 4;
    #pragma unroll
    for (int t = 0; t < 2; ++t) {
        #pragma unroll
        for (int r = 0; r < 4; ++r) {
            int row = drow0 + t * 16 + r;
            if (row < M) {
                float dval = dis[row];
                unsigned short* gp = G + (size_t)row * Nn + (lane & 15);
                #pragma unroll
                for (int ct = 0; ct < NCT; ++ct)
                    gp[ct * 16] = (unsigned short)f2bf_rne_u(acc[t][ct][r] * dval);
            }
        }
    }
}

// ================= fallback fp32 GEMM + atomic path (round-0, verified) =================

#define BM 64
#define BN 64
#define BK 16

__global__ __launch_bounds__(THREADS)
void sgemm_kernel(const float* __restrict__ A, const float* __restrict__ B,
                  float* __restrict__ C, int M, int N, int K) {
    __shared__ float As[BK][BM + 1];
    __shared__ float Bs[BK][BN + 1];

    const int tid = threadIdx.x;
    const int tr = tid / 16;
    const int tc = tid % 16;
    const int rowBase = blockIdx.y * BM;
    const int colBase = blockIdx.x * BN;

    float acc[4][4] = {};

    for (int k0 = 0; k0 < K; k0 += BK) {
        #pragma unroll
        for (int i = tid; i < BM * BK; i += THREADS) {
            int r = i / BK, c = i % BK;
            int gr = rowBase + r;
            As[c][r] = (gr < M) ? A[(size_t)gr * K + k0 + c] : 0.0f;
        }
        #pragma unroll
        for (int i = tid; i < BK * BN; i += THREADS) {
            int r = i / BN, c = i % BN;
            Bs[r][c] = B[(size_t)(k0 + r) * N + colBase + c];
        }
        __syncthreads();

        #pragma unroll
        for (int k = 0; k < BK; ++k) {
            float a[4], b[4];
            #pragma unroll
            for (int m = 0; m < 4; ++m) a[m] = As[k][tr * 4 + m];
            #pragma unroll
            for (int n = 0; n < 4; ++n) b[n] = Bs[k][tc * 4 + n];
            #pragma unroll
            for (int m = 0; m < 4; ++m)
                #pragma unroll
                for (int n = 0; n < 4; ++n)
                    acc[m][n] += a[m] * b[n];
        }
        __syncthreads();
    }

    #pragma unroll
    for (int m = 0; m < 4; ++m) {
        int gr = rowBase + tr * 4 + m;
        if (gr >= M) continue;
        #pragma unroll
        for (int n = 0; n < 4; ++n) {
            C[(size_t)gr * N + colBase + tc * 4 + n] = acc[m][n];
        }
    }
}

__global__ __launch_bounds__(THREADS)
void init_agg_kernel(const float* __restrict__ h, const float* __restrict__ dis,
                     float* __restrict__ agg, int N, int F) {
    int i = blockIdx.x * blockDim.x + threadIdx.x;
    int total = N * (F / 4);
    if (i >= total) return;
    int node = i / (F / 4);
    float d = dis[node];
    float w = d * d;
    float4 v = ((const float4*)h)[i];
    v.x *= w; v.y *= w; v.z *= w; v.w *= w;
    ((float4*)agg)[i] = v;
}

__global__ __launch_bounds__(THREADS)
void edge_scatter_kernel(const float* __restrict__ h, const int* __restrict__ src,
                         const int* __restrict__ dst, const float* __restrict__ dis,
                         float* __restrict__ agg, int E, int F) {
    int lanesPerEdge = F / 4;
    int tid = blockIdx.x * blockDim.x + threadIdx.x;
    int e = tid / lanesPerEdge;
    int c = tid % lanesPerEdge;
    if (e >= E) return;
    int s = src[e];
    int d = dst[e];
    float w = dis[s] * dis[d];
    float4 hv = ((const float4*)(h + (size_t)s * F))[c];
    float* ap = agg + (size_t)d * F + (size_t)c * 4;
    atomicAdd(ap + 0, hv.x * w);
    atomicAdd(ap + 1, hv.y * w);
    atomicAdd(ap + 2, hv.z * w);
    atomicAdd(ap + 3, hv.w * w);
}

__global__ __launch_bounds__(THREADS)
void finalize_kernel(const float* __restrict__ agg, const float* __restrict__ b,
                     float* __restrict__ out, int N, int F) {
    int i = blockIdx.x * blockDim.x + threadIdx.x;
    int total = N * (F / 4);
    if (i >= total) return;
    int c4 = i % (F / 4);
    float4 bv = ((const float4*)b)[c4];
    float4 v = ((const float4*)agg)[i];
    v.x = fmaxf(v.x + bv.x, 0.0f);
    v.y = fmaxf(v.y + bv.y, 0.0f);
    v.z = fmaxf(v.z + bv.z, 0.0f);
    v.w = fmaxf(v.w + bv.w, 0.0f);
    ((float4*)out)[i] = v;
}

__global__ __launch_bounds__(THREADS)
void fdeg_kernel(const int* __restrict__ dst, float* __restrict__ deg, int E) {
    int i = blockIdx.x * blockDim.x + threadIdx.x;
    if (i < E) atomicAdd(&deg[dst[i]], 1.0f);
}

__global__ __launch_bounds__(THREADS)
void fdis_kernel(float* __restrict__ deg, int N) {
    int i = blockIdx.x * blockDim.x + threadIdx.x;
    if (i < N) deg[i] = rsqrtf(deg[i] + 1.0f);
}

// ================= launch =================

extern "C" void kernel_launch(void* const* d_in, const int* in_sizes, int n_in,
                              void* d_out, int out_size, void* d_ws, size_t ws_size,
                              hipStream_t stream) {
    const float* x  = (const float*)d_in[0];
    const int*   ei = (const int*)d_in[1];
    const float* W1 = (const float*)d_in[2];
    const float* b1 = (const float*)d_in[3];
    const float* W2 = (const float*)d_in[4];
    const float* b2 = (const float*)d_in[5];

    const int E    = in_sizes[1] / 2;
    const int hid  = in_sizes[3];            // 128
    const int outc = in_sizes[5];            // 64
    const int inc  = in_sizes[2] / hid;      // 256
    const int N    = in_sizes[0] / inc;      // 100000

    const int* src = ei;
    const int* dst = ei + E;
    float* out = (float*)d_out;
    char* ws = (char*)d_ws;

    auto al = [](size_t v) { return (v + 255) & ~(size_t)255; };
    size_t o_dis  = 0;
    size_t o_deg  = al(o_dis + (size_t)N * 4);
    size_t o_rp   = al(o_deg + (size_t)N * 4);
    size_t o_bs   = al(o_rp + ((size_t)N + 1) * 4);
    size_t o_col  = al(o_bs + 4096);
    size_t o_rank = al(o_col + (size_t)E * 4);
    size_t o_bf1  = al(o_rank + (size_t)E * 4);
    size_t o_bf2  = al(o_bf1 + 131072);                // 8*8*1024 shorts
    size_t o_G    = al(o_bf2 + 32768);                 // 4*4*1024 shorts
    size_t o_B    = al(o_G + (size_t)N * hid * 2);     // g rows (bf16)
    size_t need   = o_B + (size_t)N * hid * 4;         // out1 (fp32)

    if (ws_size >= need && N <= SCAN_BLOCK * SCAN_BLOCK * SCAN_ITEMS &&
        hid == 128 && outc == 64 && inc == 256) {
        // ---------- CSR gather + MFMA path ----------
        float* dis    = (float*)(ws + o_dis);
        int*   deg    = (int*)(ws + o_deg);
        int*   rowptr = (int*)(ws + o_rp);
        int*   bsums  = (int*)(ws + o_bs);
        int*   col    = (int*)(ws + o_col);
        int*   rank   = (int*)(ws + o_rank);
        short* bf1    = (short*)(ws + o_bf1);
        short* bf2    = (short*)(ws + o_bf2);
        unsigned short* gbuf = (unsigned short*)(ws + o_G);  // g1 (N*128 bf16), later g2 (N*64)
        float* out1   = (float*)(ws + o_B);     // fp32 layer-1 output

        // degrees + per-edge rank
        hipMemsetAsync(deg, 0, (size_t)N * 4, stream);
        hist_rank_kernel<<<cdiv(E, THREADS), THREADS, 0, stream>>>(dst, deg, rank, E);

        // rowptr = exclusive_scan(deg); dis fused into first scan pass
        int nB = cdiv(N, SCAN_BLOCK * SCAN_ITEMS);
        scan_block_kernel<<<nB, SCAN_BLOCK, 0, stream>>>(deg, rowptr, bsums, dis, N);
        scan_sums_kernel<<<1, SCAN_BLOCK, 0, stream>>>(bsums, nB);
        scan_add_kernel<<<nB, SCAN_BLOCK, 0, stream>>>(rowptr, bsums, N, E);

        // col (sorted by dst), atomic-free
        fill_col_rank_kernel<<<cdiv(cdiv(E, 4), THREADS), THREADS, 0, stream>>>(
            src, dst, rank, rowptr, col, E);

        // weight fragments
        make_bfrag_kernel<8, 8><<<64, 64, 0, stream>>>(W1, bf1);
        make_bfrag_kernel<4, 4><<<16, 64, 0, stream>>>(W2, bf2);

        // ---- layer 1 ----
        mfma_gemm_bf16out_kernel<8, 8><<<cdiv(N, 128), THREADS, 0, stream>>>(x, bf1, gbuf, dis, N);
        gather_bf16_kernel<128, 2><<<cdiv((long long)N * 64, THREADS), THREADS, 0, stream>>>(
            gbuf, col, rowptr, dis, b1, out1, N);

        // ---- layer 2 ----
        mfma_gemm_bf16out_kernel<4, 4><<<cdiv(N, 128), THREADS, 0, stream>>>(out1, bf2, gbuf, dis, N);
        gather_bf16_kernel<64, 1><<<cdiv((long long)N * 64, THREADS), THREADS, 0, stream>>>(
            gbuf, col, rowptr, dis, b2, out, N);
        return;
    }

    // ---------- fallback: round-0 atomic path ----------
    float* dis = (float*)ws;
    size_t off1 = ((size_t)N * 4 + 255) & ~(size_t)255;
    float* h1 = (float*)(ws + off1);
    size_t off2 = off1 + ((((size_t)N * hid * 4) + 255) & ~(size_t)255);
    float* agg1 = (float*)(ws + off2);
    float* h2   = agg1;
    float* agg2 = agg1 + (size_t)N * outc;

    hipMemsetAsync(dis, 0, (size_t)N * 4, stream);
    fdeg_kernel<<<cdiv(E, THREADS), THREADS, 0, stream>>>(dst, dis, E);
    fdis_kernel<<<cdiv(N, THREADS), THREADS, 0, stream>>>(dis, N);

    {
        dim3 grid(hid / BN, cdiv(N, BM));
        sgemm_kernel<<<grid, THREADS, 0, stream>>>(x, W1, h1, N, hid, inc);
    }
    init_agg_kernel<<<cdiv((long long)N * hid / 4, THREADS), THREADS, 0, stream>>>(h1, dis, agg1, N, hid);
    edge_scatter_kernel<<<cdiv((long long)E * (hid / 4), THREADS), THREADS, 0, stream>>>(
        h1, src, dst, dis, agg1, E, hid);
    finalize_kernel<<<cdiv((long long)N * hid / 4, THREADS), THREADS, 0, stream>>>(agg1, b1, h1, N, hid);

    {
        dim3 grid(outc / BN, cdiv(N, BM));
        sgemm_kernel<<<grid, THREADS, 0, stream>>>(h1, W2, h2, N, outc, hid);
    }
    init_agg_kernel<<<cdiv((long long)N * outc / 4, THREADS), THREADS, 0, stream>>>(h2, dis, agg2, N, outc);
    edge_scatter_kernel<<<cdiv((long long)E * (outc / 4), THREADS), THREADS, 0, stream>>>(
        h2, src, dst, dis, agg2, E, outc);
    finalize_kernel<<<cdiv((long long)N * outc / 4, THREADS), THREADS, 0, stream>>>(agg2, b2, out, N, outc);
}

// Round 6
// 279.320 us; speedup vs baseline: 15.7498x; 1.3212x over previous
//
#include <hip/hip_runtime.h>
#include <math.h>

#define THREADS 256

static inline int cdiv(long long a, long long b) { return (int)((a + b - 1) / b); }

typedef __attribute__((ext_vector_type(8))) short bf16x8;
typedef __attribute__((ext_vector_type(4))) float f32x4;

__device__ inline unsigned f2bf_rne_u(float f) {
    unsigned u = __builtin_bit_cast(unsigned, f);
    return (u + 0x7FFFu + ((u >> 16) & 1u)) >> 16;
}
__device__ inline float bfu2f(unsigned h) {
    unsigned u = h << 16;
    return __builtin_bit_cast(float, u);
}

// ================= degree histogram + per-edge rank =================
// rank[e] = old count of dst[e]  (the atomic grant IS the rank within the row)

__global__ __launch_bounds__(THREADS)
void hist_rank_kernel(const int* __restrict__ dst, int* __restrict__ deg,
                      int* __restrict__ rank, int E) {
    int i = blockIdx.x * blockDim.x + threadIdx.x;
    if (i < E) rank[i] = atomicAdd(&deg[dst[i]], 1);
}

// ================= exclusive scan (N <= 256*1024), fused dis =================

#define SCAN_BLOCK 256
#define SCAN_ITEMS 4   // 1024 elements per block

__global__ __launch_bounds__(SCAN_BLOCK)
void scan_block_kernel(const int* __restrict__ in, int* __restrict__ out,
                       int* __restrict__ blockSums, float* __restrict__ dis, int n) {
    __shared__ int sdata[SCAN_BLOCK];
    int base = blockIdx.x * (SCAN_BLOCK * SCAN_ITEMS);
    int tid = threadIdx.x;
    int v[SCAN_ITEMS];
    int sum = 0;
    #pragma unroll
    for (int k = 0; k < SCAN_ITEMS; ++k) {
        int idx = base + tid * SCAN_ITEMS + k;
        v[k] = (idx < n) ? in[idx] : 0;
        if (idx < n) dis[idx] = rsqrtf((float)v[k] + 1.0f);
        sum += v[k];
    }
    sdata[tid] = sum;
    __syncthreads();
    for (int off = 1; off < SCAN_BLOCK; off <<= 1) {
        int t = (tid >= off) ? sdata[tid - off] : 0;
        __syncthreads();
        sdata[tid] += t;
        __syncthreads();
    }
    if (tid == SCAN_BLOCK - 1) blockSums[blockIdx.x] = sdata[SCAN_BLOCK - 1];
    int run = (tid == 0) ? 0 : sdata[tid - 1];
    #pragma unroll
    for (int k = 0; k < SCAN_ITEMS; ++k) {
        int idx = base + tid * SCAN_ITEMS + k;
        if (idx < n) out[idx] = run;
        run += v[k];
    }
}

__global__ __launch_bounds__(SCAN_BLOCK)
void scan_sums_kernel(int* __restrict__ blockSums, int nB) {
    __shared__ int sdata[SCAN_BLOCK];
    int tid = threadIdx.x;
    sdata[tid] = (tid < nB) ? blockSums[tid] : 0;
    __syncthreads();
    for (int off = 1; off < SCAN_BLOCK; off <<= 1) {
        int t = (tid >= off) ? sdata[tid - off] : 0;
        __syncthreads();
        sdata[tid] += t;
        __syncthreads();
    }
    int excl = (tid == 0) ? 0 : sdata[tid - 1];
    if (tid < nB) blockSums[tid] = excl;
}

__global__ __launch_bounds__(SCAN_BLOCK)
void scan_add_kernel(int* __restrict__ out, const int* __restrict__ blockSums,
                     int n, int E) {
    int base = blockIdx.x * (SCAN_BLOCK * SCAN_ITEMS);
    int add = blockSums[blockIdx.x];
    #pragma unroll
    for (int k = 0; k < SCAN_ITEMS; ++k) {
        int idx = base + threadIdx.x * SCAN_ITEMS + k;
        if (idx < n) out[idx] += add;
    }
    if (blockIdx.x == 0 && threadIdx.x == 0) out[n] = E;
}

// ================= CSR fill (atomic-free; 4 edges/thread) =================

__global__ __launch_bounds__(THREADS)
void fill_col_rank_kernel(const int* __restrict__ src, const int* __restrict__ dst,
                          const int* __restrict__ rank, const int* __restrict__ rowptr,
                          int* __restrict__ col, int E) {
    int base = (blockIdx.x * blockDim.x + threadIdx.x) * 4;
    if (base + 3 < E) {
        int4 d = *(const int4*)(dst + base);
        int4 r = *(const int4*)(rank + base);
        int4 s = *(const int4*)(src + base);
        col[rowptr[d.x] + r.x] = s.x;
        col[rowptr[d.y] + r.y] = s.y;
        col[rowptr[d.z] + r.z] = s.z;
        col[rowptr[d.w] + r.w] = s.w;
    } else {
        for (int e = base; e < E; ++e)
            col[rowptr[dst[e]] + rank[e]] = src[e];
    }
}

// ================= fused gather aggregation (bf16 pre-scaled rows) =================
// g[i] = h[i] * dis[i] (bf16). out_i = relu(dis_i * (g_i + sum_{s in N(i)} g_s) + b).
// One wave per node; VEC bf16 elems per lane (F = 64*VEC, VEC in {1,2}).
// Row bases scalarized via readfirstlane; depth-4 software pipeline (8 loads in flight).

template<int F, int VEC>
__global__ __launch_bounds__(THREADS)
void gather_bf16_kernel(const unsigned short* __restrict__ g, const int* __restrict__ col,
                        const int* __restrict__ rowptr, const float* __restrict__ dis,
                        const float* __restrict__ bias, float* __restrict__ out, int N) {
    int wid = (int)((blockIdx.x * (long long)blockDim.x + threadIdx.x) >> 6);
    wid = __builtin_amdgcn_readfirstlane(wid);
    const int lane = threadIdx.x & 63;
    if (wid >= N) return;
    const float di = dis[wid];
    const int loff = lane * VEC;

    float acc0 = 0.0f, acc1 = 0.0f;

    auto loadrow = [&](int s) -> unsigned {
        const unsigned short* p = g + (size_t)s * F + loff;
        if (VEC == 2) return *(const unsigned*)p;
        else return (unsigned)*p;
    };
    auto addconv = [&](unsigned u) {
        if (VEC == 2) {
            acc0 += bfu2f(u & 0xFFFFu);
            acc1 += __builtin_bit_cast(float, u & 0xFFFF0000u);
        } else {
            acc0 += bfu2f(u);
        }
    };

    // self-loop row
    addconv(loadrow(wid));

    int start = __builtin_amdgcn_readfirstlane(rowptr[wid]);
    int end   = __builtin_amdgcn_readfirstlane(rowptr[wid + 1]);
    const int* c = col + start;
    int rem = end - start;

    if (rem >= 4) {
        int s0 = __builtin_amdgcn_readfirstlane(c[0]);
        int s1 = __builtin_amdgcn_readfirstlane(c[1]);
        int s2 = __builtin_amdgcn_readfirstlane(c[2]);
        int s3 = __builtin_amdgcn_readfirstlane(c[3]);
        unsigned u0 = loadrow(s0), u1 = loadrow(s1), u2 = loadrow(s2), u3 = loadrow(s3);
        c += 4; rem -= 4;
        while (rem >= 4) {
            int t0 = __builtin_amdgcn_readfirstlane(c[0]);
            int t1 = __builtin_amdgcn_readfirstlane(c[1]);
            int t2 = __builtin_amdgcn_readfirstlane(c[2]);
            int t3 = __builtin_amdgcn_readfirstlane(c[3]);
            unsigned v0 = loadrow(t0), v1 = loadrow(t1), v2 = loadrow(t2), v3 = loadrow(t3);
            addconv(u0); addconv(u1); addconv(u2); addconv(u3);
            u0 = v0; u1 = v1; u2 = v2; u3 = v3;
            c += 4; rem -= 4;
        }
        addconv(u0); addconv(u1); addconv(u2); addconv(u3);
    }
    while (rem > 0) {
        int s = __builtin_amdgcn_readfirstlane(c[0]);
        addconv(loadrow(s));
        ++c; --rem;
    }

    float* orow = out + (size_t)wid * F + loff;
    float v0 = di * acc0 + bias[loff];
    if (VEC == 2) {
        float v1 = di * acc1 + bias[loff + 1];
        float2 st = make_float2(fmaxf(v0, 0.0f), fmaxf(v1, 0.0f));
        *(float2*)orow = st;
    } else {
        *orow = fmaxf(v0, 0.0f);
    }
}

// ================= split-bf16 MFMA GEMM =================
// C[M, N] = A[M, K] @ W[K, N], N = NCT*16, K = KS*32.
// 3-term split: A ~ Ahi+Alo, W ~ Whi+Wlo; C ~ AhiWhi + AhiWlo + AloWhi.
// Output: bf16 rows scaled by dis[row] (g = C*dis), feeding gather_bf16_kernel.

// Merged fragment builder: blocks 0..63 -> W1 (NCT=8,KS=8), 64..79 -> W2 (NCT=4,KS=4)
__global__ __launch_bounds__(64)
void make_bfrag_both_kernel(const float* __restrict__ W1, short* __restrict__ f1,
                            const float* __restrict__ W2, short* __restrict__ f2) {
    int lane = threadIdx.x;
    int b = blockIdx.x;
    const float* W; short* frag; int NCT, ctks;
    if (b < 64) { W = W1; frag = f1; NCT = 8; ctks = b; }
    else        { W = W2; frag = f2; NCT = 4; ctks = b - 64; }
    int Nn = NCT * 16;
    int ct = ctks % NCT;
    int ks = ctks / NCT;
    int colc = ct * 16 + (lane & 15);
    int kbase = ks * 32 + (lane >> 4) * 8;
    short* base = frag + (size_t)ctks * 1024 + lane * 8;
    #pragma unroll
    for (int j = 0; j < 8; ++j) {
        float v = W[(size_t)(kbase + j) * Nn + colc];
        unsigned h = f2bf_rne_u(v);
        base[j] = (short)h;
        base[512 + j] = (short)f2bf_rne_u(v - bfu2f(h));
    }
}

// 256 threads = 4 waves; each wave computes 32 rows (2 row-tiles) x full N.
template<int NCT, int KS>
__global__ __launch_bounds__(THREADS)
void mfma_gemm_bf16out_kernel(const float* __restrict__ A, const short* __restrict__ Bfrag,
                              unsigned short* __restrict__ G, const float* __restrict__ dis,
                              int M) {
    constexpr int K = KS * 32;
    constexpr int Nn = NCT * 16;
    const int lane = threadIdx.x & 63;
    const int wave = threadIdx.x >> 6;
    const int rowBase = blockIdx.x * 128 + wave * 32;
    const int arow0 = rowBase + (lane & 15);
    const int kgrp = (lane >> 4) * 8;

    f32x4 acc[2][NCT] = {};

    for (int ks = 0; ks < KS; ++ks) {
        const int kbase = ks * 32 + kgrp;
        bf16x8 ahi[2], alo[2];
        #pragma unroll
        for (int t = 0; t < 2; ++t) {
            int r = arow0 + t * 16;
            if (r >= M) r = M - 1;   // clamp; rows >= M masked on store
            const float* ap = A + (size_t)r * K + kbase;
            float4 v0 = *(const float4*)ap;
            float4 v1 = *(const float4*)(ap + 4);
            float av[8] = {v0.x, v0.y, v0.z, v0.w, v1.x, v1.y, v1.z, v1.w};
            #pragma unroll
            for (int j = 0; j < 8; ++j) {
                unsigned h = f2bf_rne_u(av[j]);
                ahi[t][j] = (short)h;
                alo[t][j] = (short)f2bf_rne_u(av[j] - bfu2f(h));
            }
        }
        #pragma unroll
        for (int ct = 0; ct < NCT; ++ct) {
            const short* bp = Bfrag + (size_t)(ks * NCT + ct) * 1024 + lane * 8;
            bf16x8 bhi = *(const bf16x8*)bp;
            bf16x8 blo = *(const bf16x8*)(bp + 512);
            #pragma unroll
            for (int t = 0; t < 2; ++t) {
                acc[t][ct] = __builtin_amdgcn_mfma_f32_16x16x32_bf16(ahi[t], bhi, acc[t][ct], 0, 0, 0);
                acc[t][ct] = __builtin_amdgcn_mfma_f32_16x16x32_bf16(ahi[t], blo, acc[t][ct], 0, 0, 0);
                acc[t][ct] = __builtin_amdgcn_mfma_f32_16x16x32_bf16(alo[t], bhi, acc[t][ct], 0, 0, 0);
            }
        }
    }

    // C/D layout: col = lane&15, row(within 16-tile) = (lane>>4)*4 + reg
    const int drow0 = rowBase + (lane >> 4) * 4;
    #pragma unroll
    for (int t = 0; t < 2; ++t) {
        #pragma unroll
        for (int r = 0; r < 4; ++r) {
            int row = drow0 + t * 16 + r;
            if (row < M) {
                float dval = dis[row];
                unsigned short* gp = G + (size_t)row * Nn + (lane & 15);
                #pragma unroll
                for (int ct = 0; ct < NCT; ++ct)
                    gp[ct * 16] = (unsigned short)f2bf_rne_u(acc[t][ct][r] * dval);
            }
        }
    }
}

// ================= fallback fp32 GEMM + atomic path (round-0, verified) =================

#define BM 64
#define BN 64
#define BK 16

__global__ __launch_bounds__(THREADS)
void sgemm_kernel(const float* __restrict__ A, const float* __restrict__ B,
                  float* __restrict__ C, int M, int N, int K) {
    __shared__ float As[BK][BM + 1];
    __shared__ float Bs[BK][BN + 1];

    const int tid = threadIdx.x;
    const int tr = tid / 16;
    const int tc = tid % 16;
    const int rowBase = blockIdx.y * BM;
    const int colBase = blockIdx.x * BN;

    float acc[4][4] = {};

    for (int k0 = 0; k0 < K; k0 += BK) {
        #pragma unroll
        for (int i = tid; i < BM * BK; i += THREADS) {
            int r = i / BK, c = i % BK;
            int gr = rowBase + r;
            As[c][r] = (gr < M) ? A[(size_t)gr * K + k0 + c] : 0.0f;
        }
        #pragma unroll
        for (int i = tid; i < BK * BN; i += THREADS) {
            int r = i / BN, c = i % BN;
            Bs[r][c] = B[(size_t)(k0 + r) * N + colBase + c];
        }
        __syncthreads();

        #pragma unroll
        for (int k = 0; k < BK; ++k) {
            float a[4], b[4];
            #pragma unroll
            for (int m = 0; m < 4; ++m) a[m] = As[k][tr * 4 + m];
            #pragma unroll
            for (int n = 0; n < 4; ++n) b[n] = Bs[k][tc * 4 + n];
            #pragma unroll
            for (int m = 0; m < 4; ++m)
                #pragma unroll
                for (int n = 0; n < 4; ++n)
                    acc[m][n] += a[m] * b[n];
        }
        __syncthreads();
    }

    #pragma unroll
    for (int m = 0; m < 4; ++m) {
        int gr = rowBase + tr * 4 + m;
        if (gr >= M) continue;
        #pragma unroll
        for (int n = 0; n < 4; ++n) {
            C[(size_t)gr * N + colBase + tc * 4 + n] = acc[m][n];
        }
    }
}

__global__ __launch_bounds__(THREADS)
void init_agg_kernel(const float* __restrict__ h, const float* __restrict__ dis,
                     float* __restrict__ agg, int N, int F) {
    int i = blockIdx.x * blockDim.x + threadIdx.x;
    int total = N * (F / 4);
    if (i >= total) return;
    int node = i / (F / 4);
    float d = dis[node];
    float w = d * d;
    float4 v = ((const float4*)h)[i];
    v.x *= w; v.y *= w; v.z *= w; v.w *= w;
    ((float4*)agg)[i] = v;
}

__global__ __launch_bounds__(THREADS)
void edge_scatter_kernel(const float* __restrict__ h, const int* __restrict__ src,
                         const int* __restrict__ dst, const float* __restrict__ dis,
                         float* __restrict__ agg, int E, int F) {
    int lanesPerEdge = F / 4;
    int tid = blockIdx.x * blockDim.x + threadIdx.x;
    int e = tid / lanesPerEdge;
    int c = tid % lanesPerEdge;
    if (e >= E) return;
    int s = src[e];
    int d = dst[e];
    float w = dis[s] * dis[d];
    float4 hv = ((const float4*)(h + (size_t)s * F))[c];
    float* ap = agg + (size_t)d * F + (size_t)c * 4;
    atomicAdd(ap + 0, hv.x * w);
    atomicAdd(ap + 1, hv.y * w);
    atomicAdd(ap + 2, hv.z * w);
    atomicAdd(ap + 3, hv.w * w);
}

__global__ __launch_bounds__(THREADS)
void finalize_kernel(const float* __restrict__ agg, const float* __restrict__ b,
                     float* __restrict__ out, int N, int F) {
    int i = blockIdx.x * blockDim.x + threadIdx.x;
    int total = N * (F / 4);
    if (i >= total) return;
    int c4 = i % (F / 4);
    float4 bv = ((const float4*)b)[c4];
    float4 v = ((const float4*)agg)[i];
    v.x = fmaxf(v.x + bv.x, 0.0f);
    v.y = fmaxf(v.y + bv.y, 0.0f);
    v.z = fmaxf(v.z + bv.z, 0.0f);
    v.w = fmaxf(v.w + bv.w, 0.0f);
    ((float4*)out)[i] = v;
}

__global__ __launch_bounds__(THREADS)
void fdeg_kernel(const int* __restrict__ dst, float* __restrict__ deg, int E) {
    int i = blockIdx.x * blockDim.x + threadIdx.x;
    if (i < E) atomicAdd(&deg[dst[i]], 1.0f);
}

__global__ __launch_bounds__(THREADS)
void fdis_kernel(float* __restrict__ deg, int N) {
    int i = blockIdx.x * blockDim.x + threadIdx.x;
    if (i < N) deg[i] = rsqrtf(deg[i] + 1.0f);
}

// ================= launch =================

extern "C" void kernel_launch(void* const* d_in, const int* in_sizes, int n_in,
                              void* d_out, int out_size, void* d_ws, size_t ws_size,
                              hipStream_t stream) {
    const float* x  = (const float*)d_in[0];
    const int*   ei = (const int*)d_in[1];
    const float* W1 = (const float*)d_in[2];
    const float* b1 = (const float*)d_in[3];
    const float* W2 = (const float*)d_in[4];
    const float* b2 = (const float*)d_in[5];

    const int E    = in_sizes[1] / 2;
    const int hid  = in_sizes[3];            // 128
    const int outc = in_sizes[5];            // 64
    const int inc  = in_sizes[2] / hid;      // 256
    const int N    = in_sizes[0] / inc;      // 100000

    const int* src = ei;
    const int* dst = ei + E;
    float* out = (float*)d_out;
    char* ws = (char*)d_ws;

    auto al = [](size_t v) { return (v + 255) & ~(size_t)255; };
    size_t o_dis  = 0;
    size_t o_deg  = al(o_dis + (size_t)N * 4);
    size_t o_rp   = al(o_deg + (size_t)N * 4);
    size_t o_bs   = al(o_rp + ((size_t)N + 1) * 4);
    size_t o_col  = al(o_bs + 4096);
    size_t o_rank = al(o_col + (size_t)E * 4);
    size_t o_bf1  = al(o_rank + (size_t)E * 4);
    size_t o_bf2  = al(o_bf1 + 131072);                // 8*8*1024 shorts
    size_t o_G    = al(o_bf2 + 32768);                 // 4*4*1024 shorts
    size_t o_B    = al(o_G + (size_t)N * hid * 2);     // g rows (bf16)
    size_t need   = o_B + (size_t)N * hid * 4;         // out1 (fp32)

    if (ws_size >= need && N <= SCAN_BLOCK * SCAN_BLOCK * SCAN_ITEMS &&
        hid == 128 && outc == 64 && inc == 256) {
        // ---------- CSR gather + MFMA path ----------
        float* dis    = (float*)(ws + o_dis);
        int*   deg    = (int*)(ws + o_deg);
        int*   rowptr = (int*)(ws + o_rp);
        int*   bsums  = (int*)(ws + o_bs);
        int*   col    = (int*)(ws + o_col);
        int*   rank   = (int*)(ws + o_rank);
        short* bf1    = (short*)(ws + o_bf1);
        short* bf2    = (short*)(ws + o_bf2);
        unsigned short* gbuf = (unsigned short*)(ws + o_G);  // g1 (N*128 bf16), later g2 (N*64)
        float* out1   = (float*)(ws + o_B);     // fp32 layer-1 output

        // degrees + per-edge rank
        hipMemsetAsync(deg, 0, (size_t)N * 4, stream);
        hist_rank_kernel<<<cdiv(E, THREADS), THREADS, 0, stream>>>(dst, deg, rank, E);

        // rowptr = exclusive_scan(deg); dis fused into first scan pass
        int nB = cdiv(N, SCAN_BLOCK * SCAN_ITEMS);
        scan_block_kernel<<<nB, SCAN_BLOCK, 0, stream>>>(deg, rowptr, bsums, dis, N);
        scan_sums_kernel<<<1, SCAN_BLOCK, 0, stream>>>(bsums, nB);
        scan_add_kernel<<<nB, SCAN_BLOCK, 0, stream>>>(rowptr, bsums, N, E);

        // col (sorted by dst), atomic-free
        fill_col_rank_kernel<<<cdiv(cdiv(E, 4), THREADS), THREADS, 0, stream>>>(
            src, dst, rank, rowptr, col, E);

        // weight fragments (merged launch)
        make_bfrag_both_kernel<<<80, 64, 0, stream>>>(W1, bf1, W2, bf2);

        // ---- layer 1 ----
        mfma_gemm_bf16out_kernel<8, 8><<<cdiv(N, 128), THREADS, 0, stream>>>(x, bf1, gbuf, dis, N);
        gather_bf16_kernel<128, 2><<<cdiv((long long)N * 64, THREADS), THREADS, 0, stream>>>(
            gbuf, col, rowptr, dis, b1, out1, N);

        // ---- layer 2 ----
        mfma_gemm_bf16out_kernel<4, 4><<<cdiv(N, 128), THREADS, 0, stream>>>(out1, bf2, gbuf, dis, N);
        gather_bf16_kernel<64, 1><<<cdiv((long long)N * 64, THREADS), THREADS, 0, stream>>>(
            gbuf, col, rowptr, dis, b2, out, N);
        return;
    }

    // ---------- fallback: round-0 atomic path ----------
    float* dis = (float*)ws;
    size_t off1 = ((size_t)N * 4 + 255) & ~(size_t)255;
    float* h1 = (float*)(ws + off1);
    size_t off2 = off1 + ((((size_t)N * hid * 4) + 255) & ~(size_t)255);
    float* agg1 = (float*)(ws + off2);
    float* h2   = agg1;
    float* agg2 = agg1 + (size_t)N * outc;

    hipMemsetAsync(dis, 0, (size_t)N * 4, stream);
    fdeg_kernel<<<cdiv(E, THREADS), THREADS, 0, stream>>>(dst, dis, E);
    fdis_kernel<<<cdiv(N, THREADS), THREADS, 0, stream>>>(dis, N);

    {
        dim3 grid(hid / BN, cdiv(N, BM));
        sgemm_kernel<<<grid, THREADS, 0, stream>>>(x, W1, h1, N, hid, inc);
    }
    init_agg_kernel<<<cdiv((long long)N * hid / 4, THREADS), THREADS, 0, stream>>>(h1, dis, agg1, N, hid);
    edge_scatter_kernel<<<cdiv((long long)E * (hid / 4), THREADS), THREADS, 0, stream>>>(
        h1, src, dst, dis, agg1, E, hid);
    finalize_kernel<<<cdiv((long long)N * hid / 4, THREADS), THREADS, 0, stream>>>(agg1, b1, h1, N, hid);

    {
        dim3 grid(outc / BN, cdiv(N, BM));
        sgemm_kernel<<<grid, THREADS, 0, stream>>>(h1, W2, h2, N, outc, hid);
    }
    init_agg_kernel<<<cdiv((long long)N * outc / 4, THREADS), THREADS, 0, stream>>>(h2, dis, agg2, N, outc);
    edge_scatter_kernel<<<cdiv((long long)E * (outc / 4), THREADS), THREADS, 0, stream>>>(
        h2, src, dst, dis, agg2, E, outc);
    finalize_kernel<<<cdiv((long long)N * outc / 4, THREADS), THREADS, 0, stream>>>(agg2, b2, out, N, outc);
}

// Round 7
// 273.955 us; speedup vs baseline: 16.0583x; 1.0196x over previous
//
#include <hip/hip_runtime.h>
#include <math.h>

#define THREADS 256

static inline int cdiv(long long a, long long b) { return (int)((a + b - 1) / b); }

typedef __attribute__((ext_vector_type(8))) short bf16x8;
typedef __attribute__((ext_vector_type(4))) float f32x4;

__device__ inline unsigned f2bf_rne_u(float f) {
    unsigned u = __builtin_bit_cast(unsigned, f);
    return (u + 0x7FFFu + ((u >> 16) & 1u)) >> 16;
}
__device__ inline float bfu2f(unsigned h) {
    unsigned u = h << 16;
    return __builtin_bit_cast(float, u);
}

// ================= device bodies for fused kernels =================

// histogram + rank, 4 edges/thread (4 independent atomics in flight)
__device__ __forceinline__ void hist_body(const int* __restrict__ dst, int* __restrict__ deg,
                                          int* __restrict__ rank, int E, int blk) {
    int base = (blk * THREADS + (int)threadIdx.x) * 4;
    if (base + 3 < E) {
        int4 d = *(const int4*)(dst + base);
        int4 r;
        r.x = atomicAdd(&deg[d.x], 1);
        r.y = atomicAdd(&deg[d.y], 1);
        r.z = atomicAdd(&deg[d.z], 1);
        r.w = atomicAdd(&deg[d.w], 1);
        *(int4*)(rank + base) = r;
    } else {
        for (int e = base; e < E; ++e) rank[e] = atomicAdd(&deg[dst[e]], 1);
    }
}

// one 64-lane unit builds one (hi,lo) W-fragment pair
__device__ __forceinline__ void bfrag_unit(const float* __restrict__ W, short* __restrict__ frag,
                                           int NCT, int ctks, int lane) {
    int Nn = NCT * 16;
    int ct = ctks % NCT;
    int ks = ctks / NCT;
    int colc = ct * 16 + (lane & 15);
    int kbase = ks * 32 + (lane >> 4) * 8;
    short* base = frag + (size_t)ctks * 1024 + lane * 8;
    #pragma unroll
    for (int j = 0; j < 8; ++j) {
        float v = W[(size_t)(kbase + j) * Nn + colc];
        unsigned h = f2bf_rne_u(v);
        base[j] = (short)h;
        base[512 + j] = (short)f2bf_rne_u(v - bfu2f(h));
    }
}

// CSR fill, atomic-free, 4 edges/thread
__device__ __forceinline__ void fill_body(const int* __restrict__ src, const int* __restrict__ dst,
                                          const int* __restrict__ rank, const int* __restrict__ rowptr,
                                          int* __restrict__ col, int E, int blk) {
    int base = (blk * THREADS + (int)threadIdx.x) * 4;
    if (base + 3 < E) {
        int4 d = *(const int4*)(dst + base);
        int4 r = *(const int4*)(rank + base);
        int4 s = *(const int4*)(src + base);
        col[rowptr[d.x] + r.x] = s.x;
        col[rowptr[d.y] + r.y] = s.y;
        col[rowptr[d.z] + r.z] = s.z;
        col[rowptr[d.w] + r.w] = s.w;
    } else {
        for (int e = base; e < E; ++e)
            col[rowptr[dst[e]] + rank[e]] = src[e];
    }
}

// split-bf16 MFMA GEMM body: C[M,Nn] = A[M,K] @ W; writes g = C*dis as bf16.
template<int NCT, int KS>
__device__ __forceinline__ void gemm_body(const float* __restrict__ A, const short* __restrict__ Bfrag,
                                          unsigned short* __restrict__ G, const float* __restrict__ dis,
                                          int M, int blk) {
    constexpr int K = KS * 32;
    constexpr int Nn = NCT * 16;
    const int lane = threadIdx.x & 63;
    const int wave = threadIdx.x >> 6;
    const int rowBase = blk * 128 + wave * 32;
    const int arow0 = rowBase + (lane & 15);
    const int kgrp = (lane >> 4) * 8;

    f32x4 acc[2][NCT] = {};

    for (int ks = 0; ks < KS; ++ks) {
        const int kbase = ks * 32 + kgrp;
        bf16x8 ahi[2], alo[2];
        #pragma unroll
        for (int t = 0; t < 2; ++t) {
            int r = arow0 + t * 16;
            if (r >= M) r = M - 1;   // clamp; rows >= M masked on store
            const float* ap = A + (size_t)r * K + kbase;
            float4 v0 = *(const float4*)ap;
            float4 v1 = *(const float4*)(ap + 4);
            float av[8] = {v0.x, v0.y, v0.z, v0.w, v1.x, v1.y, v1.z, v1.w};
            #pragma unroll
            for (int j = 0; j < 8; ++j) {
                unsigned h = f2bf_rne_u(av[j]);
                ahi[t][j] = (short)h;
                alo[t][j] = (short)f2bf_rne_u(av[j] - bfu2f(h));
            }
        }
        #pragma unroll
        for (int ct = 0; ct < NCT; ++ct) {
            const short* bp = Bfrag + (size_t)(ks * NCT + ct) * 1024 + lane * 8;
            bf16x8 bhi = *(const bf16x8*)bp;
            bf16x8 blo = *(const bf16x8*)(bp + 512);
            #pragma unroll
            for (int t = 0; t < 2; ++t) {
                acc[t][ct] = __builtin_amdgcn_mfma_f32_16x16x32_bf16(ahi[t], bhi, acc[t][ct], 0, 0, 0);
                acc[t][ct] = __builtin_amdgcn_mfma_f32_16x16x32_bf16(ahi[t], blo, acc[t][ct], 0, 0, 0);
                acc[t][ct] = __builtin_amdgcn_mfma_f32_16x16x32_bf16(alo[t], bhi, acc[t][ct], 0, 0, 0);
            }
        }
    }

    // C/D layout: col = lane&15, row(within 16-tile) = (lane>>4)*4 + reg
    const int drow0 = rowBase + (lane >> 4) * 4;
    #pragma unroll
    for (int t = 0; t < 2; ++t) {
        #pragma unroll
        for (int r = 0; r < 4; ++r) {
            int row = drow0 + t * 16 + r;
            if (row < M) {
                float dval = dis[row];
                unsigned short* gp = G + (size_t)row * Nn + (lane & 15);
                #pragma unroll
                for (int ct = 0; ct < NCT; ++ct)
                    gp[ct * 16] = (unsigned short)f2bf_rne_u(acc[t][ct][r] * dval);
            }
        }
    }
}

// ================= fused kernels =================

// K0: [hist blocks | bfrag blocks]
__global__ __launch_bounds__(THREADS)
void hist_bfrag_kernel(const int* __restrict__ dst, int* __restrict__ deg, int* __restrict__ rank, int E,
                       const float* __restrict__ W1, short* __restrict__ bf1,
                       const float* __restrict__ W2, short* __restrict__ bf2, int nbHist) {
    int b = (int)blockIdx.x;
    if (b < nbHist) {
        hist_body(dst, deg, rank, E, b);
    } else {
        int u = (b - nbHist) * 4 + ((int)threadIdx.x >> 6);
        int lane = threadIdx.x & 63;
        if (u < 64) bfrag_unit(W1, bf1, 8, u, lane);
        else if (u < 80) bfrag_unit(W2, bf2, 4, u - 64, lane);
    }
}

// K1: [fill_col blocks | gemm1 blocks]
template<int NCT, int KS>
__global__ __launch_bounds__(THREADS)
void fill_gemm_kernel(const int* __restrict__ src, const int* __restrict__ dst,
                      const int* __restrict__ rank, const int* __restrict__ rowptr,
                      int* __restrict__ col, int E,
                      const float* __restrict__ A, const short* __restrict__ Bfrag,
                      unsigned short* __restrict__ G, const float* __restrict__ dis,
                      int M, int nbFill) {
    int b = (int)blockIdx.x;
    if (b < nbFill) fill_body(src, dst, rank, rowptr, col, E, b);
    else gemm_body<NCT, KS>(A, Bfrag, G, dis, M, b - nbFill);
}

// standalone GEMM (layer 2)
template<int NCT, int KS>
__global__ __launch_bounds__(THREADS)
void mfma_gemm_bf16out_kernel(const float* __restrict__ A, const short* __restrict__ Bfrag,
                              unsigned short* __restrict__ G, const float* __restrict__ dis,
                              int M) {
    gemm_body<NCT, KS>(A, Bfrag, G, dis, M, (int)blockIdx.x);
}

// ================= exclusive scan (N <= 256*1024), fused dis =================

#define SCAN_BLOCK 256
#define SCAN_ITEMS 4   // 1024 elements per block

__global__ __launch_bounds__(SCAN_BLOCK)
void scan_block_kernel(const int* __restrict__ in, int* __restrict__ out,
                       int* __restrict__ blockSums, float* __restrict__ dis, int n) {
    __shared__ int sdata[SCAN_BLOCK];
    int base = blockIdx.x * (SCAN_BLOCK * SCAN_ITEMS);
    int tid = threadIdx.x;
    int v[SCAN_ITEMS];
    int sum = 0;
    #pragma unroll
    for (int k = 0; k < SCAN_ITEMS; ++k) {
        int idx = base + tid * SCAN_ITEMS + k;
        v[k] = (idx < n) ? in[idx] : 0;
        if (idx < n) dis[idx] = rsqrtf((float)v[k] + 1.0f);
        sum += v[k];
    }
    sdata[tid] = sum;
    __syncthreads();
    for (int off = 1; off < SCAN_BLOCK; off <<= 1) {
        int t = (tid >= off) ? sdata[tid - off] : 0;
        __syncthreads();
        sdata[tid] += t;
        __syncthreads();
    }
    if (tid == SCAN_BLOCK - 1) blockSums[blockIdx.x] = sdata[SCAN_BLOCK - 1];
    int run = (tid == 0) ? 0 : sdata[tid - 1];
    #pragma unroll
    for (int k = 0; k < SCAN_ITEMS; ++k) {
        int idx = base + tid * SCAN_ITEMS + k;
        if (idx < n) out[idx] = run;
        run += v[k];
    }
}

__global__ __launch_bounds__(SCAN_BLOCK)
void scan_sums_kernel(int* __restrict__ blockSums, int nB) {
    __shared__ int sdata[SCAN_BLOCK];
    int tid = threadIdx.x;
    sdata[tid] = (tid < nB) ? blockSums[tid] : 0;
    __syncthreads();
    for (int off = 1; off < SCAN_BLOCK; off <<= 1) {
        int t = (tid >= off) ? sdata[tid - off] : 0;
        __syncthreads();
        sdata[tid] += t;
        __syncthreads();
    }
    int excl = (tid == 0) ? 0 : sdata[tid - 1];
    if (tid < nB) blockSums[tid] = excl;
}

__global__ __launch_bounds__(SCAN_BLOCK)
void scan_add_kernel(int* __restrict__ out, const int* __restrict__ blockSums,
                     int n, int E) {
    int base = blockIdx.x * (SCAN_BLOCK * SCAN_ITEMS);
    int add = blockSums[blockIdx.x];
    #pragma unroll
    for (int k = 0; k < SCAN_ITEMS; ++k) {
        int idx = base + threadIdx.x * SCAN_ITEMS + k;
        if (idx < n) out[idx] += add;
    }
    if (blockIdx.x == 0 && threadIdx.x == 0) out[n] = E;
}

// ================= fused gather aggregation (bf16 pre-scaled rows) =================
// g[i] = h[i] * dis[i] (bf16). out_i = relu(dis_i * (g_i + sum_{s in N(i)} g_s) + b).
// One wave per node; scalarized row bases; depth-4 software pipeline.

template<int F, int VEC>
__global__ __launch_bounds__(THREADS)
void gather_bf16_kernel(const unsigned short* __restrict__ g, const int* __restrict__ col,
                        const int* __restrict__ rowptr, const float* __restrict__ dis,
                        const float* __restrict__ bias, float* __restrict__ out, int N) {
    int wid = (int)((blockIdx.x * (long long)blockDim.x + threadIdx.x) >> 6);
    wid = __builtin_amdgcn_readfirstlane(wid);
    const int lane = threadIdx.x & 63;
    if (wid >= N) return;
    const float di = dis[wid];
    const int loff = lane * VEC;

    float acc0 = 0.0f, acc1 = 0.0f;

    auto loadrow = [&](int s) -> unsigned {
        const unsigned short* p = g + (size_t)s * F + loff;
        if (VEC == 2) return *(const unsigned*)p;
        else return (unsigned)*p;
    };
    auto addconv = [&](unsigned u) {
        if (VEC == 2) {
            acc0 += bfu2f(u & 0xFFFFu);
            acc1 += __builtin_bit_cast(float, u & 0xFFFF0000u);
        } else {
            acc0 += bfu2f(u);
        }
    };

    // self-loop row
    addconv(loadrow(wid));

    int start = __builtin_amdgcn_readfirstlane(rowptr[wid]);
    int end   = __builtin_amdgcn_readfirstlane(rowptr[wid + 1]);
    const int* c = col + start;
    int rem = end - start;

    if (rem >= 4) {
        int s0 = __builtin_amdgcn_readfirstlane(c[0]);
        int s1 = __builtin_amdgcn_readfirstlane(c[1]);
        int s2 = __builtin_amdgcn_readfirstlane(c[2]);
        int s3 = __builtin_amdgcn_readfirstlane(c[3]);
        unsigned u0 = loadrow(s0), u1 = loadrow(s1), u2 = loadrow(s2), u3 = loadrow(s3);
        c += 4; rem -= 4;
        while (rem >= 4) {
            int t0 = __builtin_amdgcn_readfirstlane(c[0]);
            int t1 = __builtin_amdgcn_readfirstlane(c[1]);
            int t2 = __builtin_amdgcn_readfirstlane(c[2]);
            int t3 = __builtin_amdgcn_readfirstlane(c[3]);
            unsigned v0 = loadrow(t0), v1 = loadrow(t1), v2 = loadrow(t2), v3 = loadrow(t3);
            addconv(u0); addconv(u1); addconv(u2); addconv(u3);
            u0 = v0; u1 = v1; u2 = v2; u3 = v3;
            c += 4; rem -= 4;
        }
        addconv(u0); addconv(u1); addconv(u2); addconv(u3);
    }
    while (rem > 0) {
        int s = __builtin_amdgcn_readfirstlane(c[0]);
        addconv(loadrow(s));
        ++c; --rem;
    }

    float* orow = out + (size_t)wid * F + loff;
    float v0 = di * acc0 + bias[loff];
    if (VEC == 2) {
        float v1 = di * acc1 + bias[loff + 1];
        float2 st = make_float2(fmaxf(v0, 0.0f), fmaxf(v1, 0.0f));
        *(float2*)orow = st;
    } else {
        *orow = fmaxf(v0, 0.0f);
    }
}

// ================= fallback fp32 GEMM + atomic path (round-0, verified) =================

#define BM 64
#define BN 64
#define BK 16

__global__ __launch_bounds__(THREADS)
void sgemm_kernel(const float* __restrict__ A, const float* __restrict__ B,
                  float* __restrict__ C, int M, int N, int K) {
    __shared__ float As[BK][BM + 1];
    __shared__ float Bs[BK][BN + 1];

    const int tid = threadIdx.x;
    const int tr = tid / 16;
    const int tc = tid % 16;
    const int rowBase = blockIdx.y * BM;
    const int colBase = blockIdx.x * BN;

    float acc[4][4] = {};

    for (int k0 = 0; k0 < K; k0 += BK) {
        #pragma unroll
        for (int i = tid; i < BM * BK; i += THREADS) {
            int r = i / BK, c = i % BK;
            int gr = rowBase + r;
            As[c][r] = (gr < M) ? A[(size_t)gr * K + k0 + c] : 0.0f;
        }
        #pragma unroll
        for (int i = tid; i < BK * BN; i += THREADS) {
            int r = i / BN, c = i % BN;
            Bs[r][c] = B[(size_t)(k0 + r) * N + colBase + c];
        }
        __syncthreads();

        #pragma unroll
        for (int k = 0; k < BK; ++k) {
            float a[4], b[4];
            #pragma unroll
            for (int m = 0; m < 4; ++m) a[m] = As[k][tr * 4 + m];
            #pragma unroll
            for (int n = 0; n < 4; ++n) b[n] = Bs[k][tc * 4 + n];
            #pragma unroll
            for (int m = 0; m < 4; ++m)
                #pragma unroll
                for (int n = 0; n < 4; ++n)
                    acc[m][n] += a[m] * b[n];
        }
        __syncthreads();
    }

    #pragma unroll
    for (int m = 0; m < 4; ++m) {
        int gr = rowBase + tr * 4 + m;
        if (gr >= M) continue;
        #pragma unroll
        for (int n = 0; n < 4; ++n) {
            C[(size_t)gr * N + colBase + tc * 4 + n] = acc[m][n];
        }
    }
}

__global__ __launch_bounds__(THREADS)
void init_agg_kernel(const float* __restrict__ h, const float* __restrict__ dis,
                     float* __restrict__ agg, int N, int F) {
    int i = blockIdx.x * blockDim.x + threadIdx.x;
    int total = N * (F / 4);
    if (i >= total) return;
    int node = i / (F / 4);
    float d = dis[node];
    float w = d * d;
    float4 v = ((const float4*)h)[i];
    v.x *= w; v.y *= w; v.z *= w; v.w *= w;
    ((float4*)agg)[i] = v;
}

__global__ __launch_bounds__(THREADS)
void edge_scatter_kernel(const float* __restrict__ h, const int* __restrict__ src,
                         const int* __restrict__ dst, const float* __restrict__ dis,
                         float* __restrict__ agg, int E, int F) {
    int lanesPerEdge = F / 4;
    int tid = blockIdx.x * blockDim.x + threadIdx.x;
    int e = tid / lanesPerEdge;
    int c = tid % lanesPerEdge;
    if (e >= E) return;
    int s = src[e];
    int d = dst[e];
    float w = dis[s] * dis[d];
    float4 hv = ((const float4*)(h + (size_t)s * F))[c];
    float* ap = agg + (size_t)d * F + (size_t)c * 4;
    atomicAdd(ap + 0, hv.x * w);
    atomicAdd(ap + 1, hv.y * w);
    atomicAdd(ap + 2, hv.z * w);
    atomicAdd(ap + 3, hv.w * w);
}

__global__ __launch_bounds__(THREADS)
void finalize_kernel(const float* __restrict__ agg, const float* __restrict__ b,
                     float* __restrict__ out, int N, int F) {
    int i = blockIdx.x * blockDim.x + threadIdx.x;
    int total = N * (F / 4);
    if (i >= total) return;
    int c4 = i % (F / 4);
    float4 bv = ((const float4*)b)[c4];
    float4 v = ((const float4*)agg)[i];
    v.x = fmaxf(v.x + bv.x, 0.0f);
    v.y = fmaxf(v.y + bv.y, 0.0f);
    v.z = fmaxf(v.z + bv.z, 0.0f);
    v.w = fmaxf(v.w + bv.w, 0.0f);
    ((float4*)out)[i] = v;
}

__global__ __launch_bounds__(THREADS)
void fdeg_kernel(const int* __restrict__ dst, float* __restrict__ deg, int E) {
    int i = blockIdx.x * blockDim.x + threadIdx.x;
    if (i < E) atomicAdd(&deg[dst[i]], 1.0f);
}

__global__ __launch_bounds__(THREADS)
void fdis_kernel(float* __restrict__ deg, int N) {
    int i = blockIdx.x * blockDim.x + threadIdx.x;
    if (i < N) deg[i] = rsqrtf(deg[i] + 1.0f);
}

// ================= launch =================

extern "C" void kernel_launch(void* const* d_in, const int* in_sizes, int n_in,
                              void* d_out, int out_size, void* d_ws, size_t ws_size,
                              hipStream_t stream) {
    const float* x  = (const float*)d_in[0];
    const int*   ei = (const int*)d_in[1];
    const float* W1 = (const float*)d_in[2];
    const float* b1 = (const float*)d_in[3];
    const float* W2 = (const float*)d_in[4];
    const float* b2 = (const float*)d_in[5];

    const int E    = in_sizes[1] / 2;
    const int hid  = in_sizes[3];            // 128
    const int outc = in_sizes[5];            // 64
    const int inc  = in_sizes[2] / hid;      // 256
    const int N    = in_sizes[0] / inc;      // 100000

    const int* src = ei;
    const int* dst = ei + E;
    float* out = (float*)d_out;
    char* ws = (char*)d_ws;

    auto al = [](size_t v) { return (v + 255) & ~(size_t)255; };
    size_t o_dis  = 0;
    size_t o_deg  = al(o_dis + (size_t)N * 4);
    size_t o_rp   = al(o_deg + (size_t)N * 4);
    size_t o_bs   = al(o_rp + ((size_t)N + 1) * 4);
    size_t o_col  = al(o_bs + 4096);
    size_t o_rank = al(o_col + (size_t)E * 4);
    size_t o_bf1  = al(o_rank + (size_t)E * 4);
    size_t o_bf2  = al(o_bf1 + 131072);                // 8*8*1024 shorts
    size_t o_G    = al(o_bf2 + 32768);                 // 4*4*1024 shorts
    size_t o_B    = al(o_G + (size_t)N * hid * 2);     // g rows (bf16)
    size_t need   = o_B + (size_t)N * hid * 4;         // out1 (fp32)

    if (ws_size >= need && N <= SCAN_BLOCK * SCAN_BLOCK * SCAN_ITEMS &&
        hid == 128 && outc == 64 && inc == 256) {
        // ---------- CSR gather + MFMA path ----------
        float* dis    = (float*)(ws + o_dis);
        int*   deg    = (int*)(ws + o_deg);
        int*   rowptr = (int*)(ws + o_rp);
        int*   bsums  = (int*)(ws + o_bs);
        int*   col    = (int*)(ws + o_col);
        int*   rank   = (int*)(ws + o_rank);
        short* bf1    = (short*)(ws + o_bf1);
        short* bf2    = (short*)(ws + o_bf2);
        unsigned short* gbuf = (unsigned short*)(ws + o_G);  // g1 (N*128 bf16), later g2 (N*64)
        float* out1   = (float*)(ws + o_B);     // fp32 layer-1 output

        const int nbHist = cdiv(E, 4 * THREADS);
        const int nbFill = cdiv(E, 4 * THREADS);
        const int nbGemm1 = cdiv(N, 128);

        // K0: degrees+rank (ILP-4) || weight fragments
        hipMemsetAsync(deg, 0, (size_t)N * 4, stream);
        hist_bfrag_kernel<<<nbHist + 20, THREADS, 0, stream>>>(
            dst, deg, rank, E, W1, bf1, W2, bf2, nbHist);

        // rowptr = exclusive_scan(deg); dis fused into first scan pass
        int nB = cdiv(N, SCAN_BLOCK * SCAN_ITEMS);
        scan_block_kernel<<<nB, SCAN_BLOCK, 0, stream>>>(deg, rowptr, bsums, dis, N);
        scan_sums_kernel<<<1, SCAN_BLOCK, 0, stream>>>(bsums, nB);
        scan_add_kernel<<<nB, SCAN_BLOCK, 0, stream>>>(rowptr, bsums, N, E);

        // K1: CSR fill || layer-1 GEMM
        fill_gemm_kernel<8, 8><<<nbFill + nbGemm1, THREADS, 0, stream>>>(
            src, dst, rank, rowptr, col, E, x, bf1, gbuf, dis, N, nbFill);

        gather_bf16_kernel<128, 2><<<cdiv((long long)N * 64, THREADS), THREADS, 0, stream>>>(
            gbuf, col, rowptr, dis, b1, out1, N);

        // ---- layer 2 ----
        mfma_gemm_bf16out_kernel<4, 4><<<cdiv(N, 128), THREADS, 0, stream>>>(out1, bf2, gbuf, dis, N);
        gather_bf16_kernel<64, 1><<<cdiv((long long)N * 64, THREADS), THREADS, 0, stream>>>(
            gbuf, col, rowptr, dis, b2, out, N);
        return;
    }

    // ---------- fallback: round-0 atomic path ----------
    float* dis = (float*)ws;
    size_t off1 = ((size_t)N * 4 + 255) & ~(size_t)255;
    float* h1 = (float*)(ws + off1);
    size_t off2 = off1 + ((((size_t)N * hid * 4) + 255) & ~(size_t)255);
    float* agg1 = (float*)(ws + off2);
    float* h2   = agg1;
    float* agg2 = agg1 + (size_t)N * outc;

    hipMemsetAsync(dis, 0, (size_t)N * 4, stream);
    fdeg_kernel<<<cdiv(E, THREADS), THREADS, 0, stream>>>(dst, dis, E);
    fdis_kernel<<<cdiv(N, THREADS), THREADS, 0, stream>>>(dis, N);

    {
        dim3 grid(hid / BN, cdiv(N, BM));
        sgemm_kernel<<<grid, THREADS, 0, stream>>>(x, W1, h1, N, hid, inc);
    }
    init_agg_kernel<<<cdiv((long long)N * hid / 4, THREADS), THREADS, 0, stream>>>(h1, dis, agg1, N, hid);
    edge_scatter_kernel<<<cdiv((long long)E * (hid / 4), THREADS), THREADS, 0, stream>>>(
        h1, src, dst, dis, agg1, E, hid);
    finalize_kernel<<<cdiv((long long)N * hid / 4, THREADS), THREADS, 0, stream>>>(agg1, b1, h1, N, hid);

    {
        dim3 grid(outc / BN, cdiv(N, BM));
        sgemm_kernel<<<grid, THREADS, 0, stream>>>(h1, W2, h2, N, outc, hid);
    }
    init_agg_kernel<<<cdiv((long long)N * outc / 4, THREADS), THREADS, 0, stream>>>(h2, dis, agg2, N, outc);
    edge_scatter_kernel<<<cdiv((long long)E * (outc / 4), THREADS), THREADS, 0, stream>>>(
        h2, src, dst, dis, agg2, E, outc);
    finalize_kernel<<<cdiv((long long)N * outc / 4, THREADS), THREADS, 0, stream>>>(agg2, b2, out, N, outc);
}

// Round 8
// 260.062 us; speedup vs baseline: 16.9161x; 1.0534x over previous
//
#include <hip/hip_runtime.h>
#include <math.h>

#define THREADS 256

static inline int cdiv(long long a, long long b) { return (int)((a + b - 1) / b); }

typedef __attribute__((ext_vector_type(8))) short bf16x8;
typedef __attribute__((ext_vector_type(4))) float f32x4;

__device__ inline unsigned f2bf_rne_u(float f) {
    unsigned u = __builtin_bit_cast(unsigned, f);
    return (u + 0x7FFFu + ((u >> 16) & 1u)) >> 16;
}
__device__ inline float bfu2f(unsigned h) {
    unsigned u = h << 16;
    return __builtin_bit_cast(float, u);
}

// ================= device bodies =================

// histogram + rank, 8 edges/thread (8 independent atomics in flight)
__device__ __forceinline__ void hist_body8(const int* __restrict__ dst, int* __restrict__ deg,
                                           int* __restrict__ rank, int E, int blk) {
    int base = (blk * THREADS + (int)threadIdx.x) * 8;
    if (base + 7 < E) {
        int4 d0 = *(const int4*)(dst + base);
        int4 d1 = *(const int4*)(dst + base + 4);
        int4 r0, r1;
        r0.x = atomicAdd(&deg[d0.x], 1);
        r0.y = atomicAdd(&deg[d0.y], 1);
        r0.z = atomicAdd(&deg[d0.z], 1);
        r0.w = atomicAdd(&deg[d0.w], 1);
        r1.x = atomicAdd(&deg[d1.x], 1);
        r1.y = atomicAdd(&deg[d1.y], 1);
        r1.z = atomicAdd(&deg[d1.z], 1);
        r1.w = atomicAdd(&deg[d1.w], 1);
        *(int4*)(rank + base) = r0;
        *(int4*)(rank + base + 4) = r1;
    } else {
        for (int e = base; e < E; ++e) rank[e] = atomicAdd(&deg[dst[e]], 1);
    }
}

// one 64-lane unit builds one (hi,lo) W-fragment pair
__device__ __forceinline__ void bfrag_unit(const float* __restrict__ W, short* __restrict__ frag,
                                           int NCT, int ctks, int lane) {
    int Nn = NCT * 16;
    int ct = ctks % NCT;
    int ks = ctks / NCT;
    int colc = ct * 16 + (lane & 15);
    int kbase = ks * 32 + (lane >> 4) * 8;
    short* base = frag + (size_t)ctks * 1024 + lane * 8;
    #pragma unroll
    for (int j = 0; j < 8; ++j) {
        float v = W[(size_t)(kbase + j) * Nn + colc];
        unsigned h = f2bf_rne_u(v);
        base[j] = (short)h;
        base[512 + j] = (short)f2bf_rne_u(v - bfu2f(h));
    }
}

// CSR fill, atomic-free, 4 edges/thread
__device__ __forceinline__ void fill_body(const int* __restrict__ src, const int* __restrict__ dst,
                                          const int* __restrict__ rank, const int* __restrict__ rowptr,
                                          int* __restrict__ col, int E, int blk) {
    int base = (blk * THREADS + (int)threadIdx.x) * 4;
    if (base + 3 < E) {
        int4 d = *(const int4*)(dst + base);
        int4 r = *(const int4*)(rank + base);
        int4 s = *(const int4*)(src + base);
        col[rowptr[d.x] + r.x] = s.x;
        col[rowptr[d.y] + r.y] = s.y;
        col[rowptr[d.z] + r.z] = s.z;
        col[rowptr[d.w] + r.w] = s.w;
    } else {
        for (int e = base; e < E; ++e)
            col[rowptr[dst[e]] + rank[e]] = src[e];
    }
}

// split-bf16 MFMA GEMM body: writes H = bf16(A @ W), UNSCALED.
template<int NCT, int KS>
__device__ __forceinline__ void gemm_body(const float* __restrict__ A, const short* __restrict__ Bfrag,
                                          unsigned short* __restrict__ H, int M, int blk) {
    constexpr int K = KS * 32;
    constexpr int Nn = NCT * 16;
    const int lane = threadIdx.x & 63;
    const int wave = threadIdx.x >> 6;
    const int rowBase = blk * 128 + wave * 32;
    const int arow0 = rowBase + (lane & 15);
    const int kgrp = (lane >> 4) * 8;

    f32x4 acc[2][NCT] = {};

    for (int ks = 0; ks < KS; ++ks) {
        const int kbase = ks * 32 + kgrp;
        bf16x8 ahi[2], alo[2];
        #pragma unroll
        for (int t = 0; t < 2; ++t) {
            int r = arow0 + t * 16;
            if (r >= M) r = M - 1;   // clamp; rows >= M masked on store
            const float* ap = A + (size_t)r * K + kbase;
            float4 v0 = *(const float4*)ap;
            float4 v1 = *(const float4*)(ap + 4);
            float av[8] = {v0.x, v0.y, v0.z, v0.w, v1.x, v1.y, v1.z, v1.w};
            #pragma unroll
            for (int j = 0; j < 8; ++j) {
                unsigned h = f2bf_rne_u(av[j]);
                ahi[t][j] = (short)h;
                alo[t][j] = (short)f2bf_rne_u(av[j] - bfu2f(h));
            }
        }
        #pragma unroll
        for (int ct = 0; ct < NCT; ++ct) {
            const short* bp = Bfrag + (size_t)(ks * NCT + ct) * 1024 + lane * 8;
            bf16x8 bhi = *(const bf16x8*)bp;
            bf16x8 blo = *(const bf16x8*)(bp + 512);
            #pragma unroll
            for (int t = 0; t < 2; ++t) {
                acc[t][ct] = __builtin_amdgcn_mfma_f32_16x16x32_bf16(ahi[t], bhi, acc[t][ct], 0, 0, 0);
                acc[t][ct] = __builtin_amdgcn_mfma_f32_16x16x32_bf16(ahi[t], blo, acc[t][ct], 0, 0, 0);
                acc[t][ct] = __builtin_amdgcn_mfma_f32_16x16x32_bf16(alo[t], bhi, acc[t][ct], 0, 0, 0);
            }
        }
    }

    // C/D layout: col = lane&15, row(within 16-tile) = (lane>>4)*4 + reg
    const int drow0 = rowBase + (lane >> 4) * 4;
    #pragma unroll
    for (int t = 0; t < 2; ++t) {
        #pragma unroll
        for (int r = 0; r < 4; ++r) {
            int row = drow0 + t * 16 + r;
            if (row < M) {
                unsigned short* hp = H + (size_t)row * Nn + (lane & 15);
                #pragma unroll
                for (int ct = 0; ct < NCT; ++ct)
                    hp[ct * 16] = (unsigned short)f2bf_rne_u(acc[t][ct][r]);
            }
        }
    }
}

// ================= fused kernels =================

// K0: [zero-deg blocks | bfrag blocks]
__global__ __launch_bounds__(THREADS)
void zero_bfrag_kernel(int* __restrict__ deg, int N,
                       const float* __restrict__ W1, short* __restrict__ bf1,
                       const float* __restrict__ W2, short* __restrict__ bf2, int nbZero) {
    int b = (int)blockIdx.x;
    if (b < nbZero) {
        int base = (b * THREADS + (int)threadIdx.x) * 4;
        if (base + 3 < N) {
            *(int4*)(deg + base) = make_int4(0, 0, 0, 0);
        } else {
            for (int i = base; i < N; ++i) deg[i] = 0;
        }
    } else {
        int u = (b - nbZero) * 4 + ((int)threadIdx.x >> 6);
        int lane = threadIdx.x & 63;
        if (u < 64) bfrag_unit(W1, bf1, 8, u, lane);
        else if (u < 80) bfrag_unit(W2, bf2, 4, u - 64, lane);
    }
}

// K1: [hist || gemm1] — Bresenham-interleaved roles for true co-residence
__global__ __launch_bounds__(THREADS)
void hist_gemm1_kernel(const int* __restrict__ dst, int* __restrict__ deg,
                       int* __restrict__ rank, int E,
                       const float* __restrict__ A, const short* __restrict__ Bfrag,
                       unsigned short* __restrict__ H, int M,
                       int nbHist, int nbGemm) {
    int b = (int)blockIdx.x;
    int total = nbHist + nbGemm;
    long long t = (long long)b * nbGemm;
    int gBefore = (int)(t / total);
    bool isG = (((long long)(b + 1) * nbGemm) / total) > gBefore;
    if (isG) gemm_body<8, 8>(A, Bfrag, H, M, gBefore);
    else     hist_body8(dst, deg, rank, E, b - gBefore);
}

// CSR fill standalone
__global__ __launch_bounds__(THREADS)
void fill_col_rank_kernel(const int* __restrict__ src, const int* __restrict__ dst,
                          const int* __restrict__ rank, const int* __restrict__ rowptr,
                          int* __restrict__ col, int E) {
    fill_body(src, dst, rank, rowptr, col, E, (int)blockIdx.x);
}

// standalone GEMM (layer 2)
template<int NCT, int KS>
__global__ __launch_bounds__(THREADS)
void mfma_gemm_bf16out_kernel(const float* __restrict__ A, const short* __restrict__ Bfrag,
                              unsigned short* __restrict__ H, int M) {
    gemm_body<NCT, KS>(A, Bfrag, H, M, (int)blockIdx.x);
}

// ================= exclusive scan (N <= 256*1024), fused dis =================

#define SCAN_BLOCK 256
#define SCAN_ITEMS 4   // 1024 elements per block

__global__ __launch_bounds__(SCAN_BLOCK)
void scan_block_kernel(const int* __restrict__ in, int* __restrict__ out,
                       int* __restrict__ blockSums, float* __restrict__ dis, int n) {
    __shared__ int sdata[SCAN_BLOCK];
    int base = blockIdx.x * (SCAN_BLOCK * SCAN_ITEMS);
    int tid = threadIdx.x;
    int v[SCAN_ITEMS];
    int sum = 0;
    #pragma unroll
    for (int k = 0; k < SCAN_ITEMS; ++k) {
        int idx = base + tid * SCAN_ITEMS + k;
        v[k] = (idx < n) ? in[idx] : 0;
        if (idx < n) dis[idx] = rsqrtf((float)v[k] + 1.0f);
        sum += v[k];
    }
    sdata[tid] = sum;
    __syncthreads();
    for (int off = 1; off < SCAN_BLOCK; off <<= 1) {
        int t = (tid >= off) ? sdata[tid - off] : 0;
        __syncthreads();
        sdata[tid] += t;
        __syncthreads();
    }
    if (tid == SCAN_BLOCK - 1) blockSums[blockIdx.x] = sdata[SCAN_BLOCK - 1];
    int run = (tid == 0) ? 0 : sdata[tid - 1];
    #pragma unroll
    for (int k = 0; k < SCAN_ITEMS; ++k) {
        int idx = base + tid * SCAN_ITEMS + k;
        if (idx < n) out[idx] = run;
        run += v[k];
    }
}

__global__ __launch_bounds__(SCAN_BLOCK)
void scan_sums_kernel(int* __restrict__ blockSums, int nB) {
    __shared__ int sdata[SCAN_BLOCK];
    int tid = threadIdx.x;
    sdata[tid] = (tid < nB) ? blockSums[tid] : 0;
    __syncthreads();
    for (int off = 1; off < SCAN_BLOCK; off <<= 1) {
        int t = (tid >= off) ? sdata[tid - off] : 0;
        __syncthreads();
        sdata[tid] += t;
        __syncthreads();
    }
    int excl = (tid == 0) ? 0 : sdata[tid - 1];
    if (tid < nB) blockSums[tid] = excl;
}

__global__ __launch_bounds__(SCAN_BLOCK)
void scan_add_kernel(int* __restrict__ out, const int* __restrict__ blockSums,
                     int n, int E) {
    int base = blockIdx.x * (SCAN_BLOCK * SCAN_ITEMS);
    int add = blockSums[blockIdx.x];
    #pragma unroll
    for (int k = 0; k < SCAN_ITEMS; ++k) {
        int idx = base + threadIdx.x * SCAN_ITEMS + k;
        if (idx < n) out[idx] += add;
    }
    if (blockIdx.x == 0 && threadIdx.x == 0) out[n] = E;
}

// ================= fused gather aggregation (bf16 UNSCALED rows) =================
// out_i = relu(di * (di*h_i + sum_s dis[s]*h_s) + b).
// One wave per node; scalarized row bases + scalar dis[s]; depth-4 pipeline.

template<int F, int VEC>
__global__ __launch_bounds__(THREADS)
void gather_bf16_kernel(const unsigned short* __restrict__ g, const int* __restrict__ col,
                        const int* __restrict__ rowptr, const float* __restrict__ dis,
                        const float* __restrict__ bias, float* __restrict__ out, int N) {
    int wid = (int)((blockIdx.x * (long long)blockDim.x + threadIdx.x) >> 6);
    wid = __builtin_amdgcn_readfirstlane(wid);
    const int lane = threadIdx.x & 63;
    if (wid >= N) return;
    const float di = dis[wid];
    const int loff = lane * VEC;

    float acc0 = 0.0f, acc1 = 0.0f;

    auto loadrow = [&](int s) -> unsigned {
        const unsigned short* p = g + (size_t)s * F + loff;
        if (VEC == 2) return *(const unsigned*)p;
        else return (unsigned)*p;
    };
    auto addconv = [&](unsigned u, float w) {
        if (VEC == 2) {
            acc0 += w * bfu2f(u & 0xFFFFu);
            acc1 += w * __builtin_bit_cast(float, u & 0xFFFF0000u);
        } else {
            acc0 += w * bfu2f(u);
        }
    };

    // self-loop row (weight di)
    addconv(loadrow(wid), di);

    int start = __builtin_amdgcn_readfirstlane(rowptr[wid]);
    int end   = __builtin_amdgcn_readfirstlane(rowptr[wid + 1]);
    const int* c = col + start;
    int rem = end - start;

    if (rem >= 4) {
        int s0 = __builtin_amdgcn_readfirstlane(c[0]);
        int s1 = __builtin_amdgcn_readfirstlane(c[1]);
        int s2 = __builtin_amdgcn_readfirstlane(c[2]);
        int s3 = __builtin_amdgcn_readfirstlane(c[3]);
        float w0 = dis[s0], w1 = dis[s1], w2 = dis[s2], w3 = dis[s3];
        unsigned u0 = loadrow(s0), u1 = loadrow(s1), u2 = loadrow(s2), u3 = loadrow(s3);
        c += 4; rem -= 4;
        while (rem >= 4) {
            int t0 = __builtin_amdgcn_readfirstlane(c[0]);
            int t1 = __builtin_amdgcn_readfirstlane(c[1]);
            int t2 = __builtin_amdgcn_readfirstlane(c[2]);
            int t3 = __builtin_amdgcn_readfirstlane(c[3]);
            float x0 = dis[t0], x1 = dis[t1], x2 = dis[t2], x3 = dis[t3];
            unsigned v0 = loadrow(t0), v1 = loadrow(t1), v2 = loadrow(t2), v3 = loadrow(t3);
            addconv(u0, w0); addconv(u1, w1); addconv(u2, w2); addconv(u3, w3);
            u0 = v0; u1 = v1; u2 = v2; u3 = v3;
            w0 = x0; w1 = x1; w2 = x2; w3 = x3;
            c += 4; rem -= 4;
        }
        addconv(u0, w0); addconv(u1, w1); addconv(u2, w2); addconv(u3, w3);
    }
    while (rem > 0) {
        int s = __builtin_amdgcn_readfirstlane(c[0]);
        addconv(loadrow(s), dis[s]);
        ++c; --rem;
    }

    float* orow = out + (size_t)wid * F + loff;
    float v0 = di * acc0 + bias[loff];
    if (VEC == 2) {
        float v1 = di * acc1 + bias[loff + 1];
        float2 st = make_float2(fmaxf(v0, 0.0f), fmaxf(v1, 0.0f));
        *(float2*)orow = st;
    } else {
        *orow = fmaxf(v0, 0.0f);
    }
}

// ================= fallback fp32 GEMM + atomic path (round-0, verified) =================

#define BM 64
#define BN 64
#define BK 16

__global__ __launch_bounds__(THREADS)
void sgemm_kernel(const float* __restrict__ A, const float* __restrict__ B,
                  float* __restrict__ C, int M, int N, int K) {
    __shared__ float As[BK][BM + 1];
    __shared__ float Bs[BK][BN + 1];

    const int tid = threadIdx.x;
    const int tr = tid / 16;
    const int tc = tid % 16;
    const int rowBase = blockIdx.y * BM;
    const int colBase = blockIdx.x * BN;

    float acc[4][4] = {};

    for (int k0 = 0; k0 < K; k0 += BK) {
        #pragma unroll
        for (int i = tid; i < BM * BK; i += THREADS) {
            int r = i / BK, c = i % BK;
            int gr = rowBase + r;
            As[c][r] = (gr < M) ? A[(size_t)gr * K + k0 + c] : 0.0f;
        }
        #pragma unroll
        for (int i = tid; i < BK * BN; i += THREADS) {
            int r = i / BN, c = i % BN;
            Bs[r][c] = B[(size_t)(k0 + r) * N + colBase + c];
        }
        __syncthreads();

        #pragma unroll
        for (int k = 0; k < BK; ++k) {
            float a[4], b[4];
            #pragma unroll
            for (int m = 0; m < 4; ++m) a[m] = As[k][tr * 4 + m];
            #pragma unroll
            for (int n = 0; n < 4; ++n) b[n] = Bs[k][tc * 4 + n];
            #pragma unroll
            for (int m = 0; m < 4; ++m)
                #pragma unroll
                for (int n = 0; n < 4; ++n)
                    acc[m][n] += a[m] * b[n];
        }
        __syncthreads();
    }

    #pragma unroll
    for (int m = 0; m < 4; ++m) {
        int gr = rowBase + tr * 4 + m;
        if (gr >= M) continue;
        #pragma unroll
        for (int n = 0; n < 4; ++n) {
            C[(size_t)gr * N + colBase + tc * 4 + n] = acc[m][n];
        }
    }
}

__global__ __launch_bounds__(THREADS)
void init_agg_kernel(const float* __restrict__ h, const float* __restrict__ dis,
                     float* __restrict__ agg, int N, int F) {
    int i = blockIdx.x * blockDim.x + threadIdx.x;
    int total = N * (F / 4);
    if (i >= total) return;
    int node = i / (F / 4);
    float d = dis[node];
    float w = d * d;
    float4 v = ((const float4*)h)[i];
    v.x *= w; v.y *= w; v.z *= w; v.w *= w;
    ((float4*)agg)[i] = v;
}

__global__ __launch_bounds__(THREADS)
void edge_scatter_kernel(const float* __restrict__ h, const int* __restrict__ src,
                         const int* __restrict__ dst, const float* __restrict__ dis,
                         float* __restrict__ agg, int E, int F) {
    int lanesPerEdge = F / 4;
    int tid = blockIdx.x * blockDim.x + threadIdx.x;
    int e = tid / lanesPerEdge;
    int c = tid % lanesPerEdge;
    if (e >= E) return;
    int s = src[e];
    int d = dst[e];
    float w = dis[s] * dis[d];
    float4 hv = ((const float4*)(h + (size_t)s * F))[c];
    float* ap = agg + (size_t)d * F + (size_t)c * 4;
    atomicAdd(ap + 0, hv.x * w);
    atomicAdd(ap + 1, hv.y * w);
    atomicAdd(ap + 2, hv.z * w);
    atomicAdd(ap + 3, hv.w * w);
}

__global__ __launch_bounds__(THREADS)
void finalize_kernel(const float* __restrict__ agg, const float* __restrict__ b,
                     float* __restrict__ out, int N, int F) {
    int i = blockIdx.x * blockDim.x + threadIdx.x;
    int total = N * (F / 4);
    if (i >= total) return;
    int c4 = i % (F / 4);
    float4 bv = ((const float4*)b)[c4];
    float4 v = ((const float4*)agg)[i];
    v.x = fmaxf(v.x + bv.x, 0.0f);
    v.y = fmaxf(v.y + bv.y, 0.0f);
    v.z = fmaxf(v.z + bv.z, 0.0f);
    v.w = fmaxf(v.w + bv.w, 0.0f);
    ((float4*)out)[i] = v;
}

__global__ __launch_bounds__(THREADS)
void fdeg_kernel(const int* __restrict__ dst, float* __restrict__ deg, int E) {
    int i = blockIdx.x * blockDim.x + threadIdx.x;
    if (i < E) atomicAdd(&deg[dst[i]], 1.0f);
}

__global__ __launch_bounds__(THREADS)
void fdis_kernel(float* __restrict__ deg, int N) {
    int i = blockIdx.x * blockDim.x + threadIdx.x;
    if (i < N) deg[i] = rsqrtf(deg[i] + 1.0f);
}

// ================= launch =================

extern "C" void kernel_launch(void* const* d_in, const int* in_sizes, int n_in,
                              void* d_out, int out_size, void* d_ws, size_t ws_size,
                              hipStream_t stream) {
    const float* x  = (const float*)d_in[0];
    const int*   ei = (const int*)d_in[1];
    const float* W1 = (const float*)d_in[2];
    const float* b1 = (const float*)d_in[3];
    const float* W2 = (const float*)d_in[4];
    const float* b2 = (const float*)d_in[5];

    const int E    = in_sizes[1] / 2;
    const int hid  = in_sizes[3];            // 128
    const int outc = in_sizes[5];            // 64
    const int inc  = in_sizes[2] / hid;      // 256
    const int N    = in_sizes[0] / inc;      // 100000

    const int* src = ei;
    const int* dst = ei + E;
    float* out = (float*)d_out;
    char* ws = (char*)d_ws;

    auto al = [](size_t v) { return (v + 255) & ~(size_t)255; };
    size_t o_dis  = 0;
    size_t o_deg  = al(o_dis + (size_t)N * 4);
    size_t o_rp   = al(o_deg + (size_t)N * 4);
    size_t o_bs   = al(o_rp + ((size_t)N + 1) * 4);
    size_t o_col  = al(o_bs + 4096);
    size_t o_rank = al(o_col + (size_t)E * 4);
    size_t o_bf1  = al(o_rank + (size_t)E * 4);
    size_t o_bf2  = al(o_bf1 + 131072);                // 8*8*1024 shorts
    size_t o_G    = al(o_bf2 + 32768);                 // 4*4*1024 shorts
    size_t o_B    = al(o_G + (size_t)N * hid * 2);     // h rows (bf16)
    size_t need   = o_B + (size_t)N * hid * 4;         // out1 (fp32)

    if (ws_size >= need && N <= SCAN_BLOCK * SCAN_BLOCK * SCAN_ITEMS &&
        hid == 128 && outc == 64 && inc == 256) {
        // ---------- CSR gather + MFMA path ----------
        float* dis    = (float*)(ws + o_dis);
        int*   deg    = (int*)(ws + o_deg);
        int*   rowptr = (int*)(ws + o_rp);
        int*   bsums  = (int*)(ws + o_bs);
        int*   col    = (int*)(ws + o_col);
        int*   rank   = (int*)(ws + o_rank);
        short* bf1    = (short*)(ws + o_bf1);
        short* bf2    = (short*)(ws + o_bf2);
        unsigned short* gbuf = (unsigned short*)(ws + o_G);  // h1 bf16 (N*128), later h2 (N*64)
        float* out1   = (float*)(ws + o_B);     // fp32 layer-1 output

        const int nbZero  = cdiv(N, 4 * THREADS);
        const int nbHist  = cdiv(E, 8 * THREADS);
        const int nbGemm1 = cdiv(N, 128);
        const int nbFill  = cdiv(E, 4 * THREADS);

        // K0: zero deg || weight fragments
        zero_bfrag_kernel<<<nbZero + 20, THREADS, 0, stream>>>(deg, N, W1, bf1, W2, bf2, nbZero);

        // K1: hist (ILP-8) || gemm1 (interleaved roles, co-resident)
        hist_gemm1_kernel<<<nbHist + nbGemm1, THREADS, 0, stream>>>(
            dst, deg, rank, E, x, bf1, gbuf, N, nbHist, nbGemm1);

        // rowptr = exclusive_scan(deg); dis fused into first scan pass
        int nB = cdiv(N, SCAN_BLOCK * SCAN_ITEMS);
        scan_block_kernel<<<nB, SCAN_BLOCK, 0, stream>>>(deg, rowptr, bsums, dis, N);
        scan_sums_kernel<<<1, SCAN_BLOCK, 0, stream>>>(bsums, nB);
        scan_add_kernel<<<nB, SCAN_BLOCK, 0, stream>>>(rowptr, bsums, N, E);

        // CSR fill (atomic-free)
        fill_col_rank_kernel<<<nbFill, THREADS, 0, stream>>>(src, dst, rank, rowptr, col, E);

        // ---- layer 1 gather ----
        gather_bf16_kernel<128, 2><<<cdiv((long long)N * 64, THREADS), THREADS, 0, stream>>>(
            gbuf, col, rowptr, dis, b1, out1, N);

        // ---- layer 2 ----
        mfma_gemm_bf16out_kernel<4, 4><<<cdiv(N, 128), THREADS, 0, stream>>>(out1, bf2, gbuf, N);
        gather_bf16_kernel<64, 1><<<cdiv((long long)N * 64, THREADS), THREADS, 0, stream>>>(
            gbuf, col, rowptr, dis, b2, out, N);
        return;
    }

    // ---------- fallback: round-0 atomic path ----------
    float* dis = (float*)ws;
    size_t off1 = ((size_t)N * 4 + 255) & ~(size_t)255;
    float* h1 = (float*)(ws + off1);
    size_t off2 = off1 + ((((size_t)N * hid * 4) + 255) & ~(size_t)255);
    float* agg1 = (float*)(ws + off2);
    float* h2   = agg1;
    float* agg2 = agg1 + (size_t)N * outc;

    hipMemsetAsync(dis, 0, (size_t)N * 4, stream);
    fdeg_kernel<<<cdiv(E, THREADS), THREADS, 0, stream>>>(dst, dis, E);
    fdis_kernel<<<cdiv(N, THREADS), THREADS, 0, stream>>>(dis, N);

    {
        dim3 grid(hid / BN, cdiv(N, BM));
        sgemm_kernel<<<grid, THREADS, 0, stream>>>(x, W1, h1, N, hid, inc);
    }
    init_agg_kernel<<<cdiv((long long)N * hid / 4, THREADS), THREADS, 0, stream>>>(h1, dis, agg1, N, hid);
    edge_scatter_kernel<<<cdiv((long long)E * (hid / 4), THREADS), THREADS, 0, stream>>>(
        h1, src, dst, dis, agg1, E, hid);
    finalize_kernel<<<cdiv((long long)N * hid / 4, THREADS), THREADS, 0, stream>>>(agg1, b1, h1, N, hid);

    {
        dim3 grid(outc / BN, cdiv(N, BM));
        sgemm_kernel<<<grid, THREADS, 0, stream>>>(h1, W2, h2, N, outc, hid);
    }
    init_agg_kernel<<<cdiv((long long)N * outc / 4, THREADS), THREADS, 0, stream>>>(h2, dis, agg2, N, outc);
    edge_scatter_kernel<<<cdiv((long long)E * (outc / 4), THREADS), THREADS, 0, stream>>>(
        h2, src, dst, dis, agg2, E, outc);
    finalize_kernel<<<cdiv((long long)N * outc / 4, THREADS), THREADS, 0, stream>>>(agg2, b2, out, N, outc);
}